// Round 7
// baseline (273.510 us; speedup 1.0000x reference)
//
#include <hip/hip_runtime.h>
#include <stdint.h>

typedef unsigned long long u64;
typedef unsigned int u32;

#define BATCH 4
#define NANCH 230400          // 160*160*9
#define NBLK  900             // blocks of 256 per image (exact)
#define SELCAP 8192           // selection buffer cap per image
#define CPROC 4096            // candidates covered by pairwise bitmask (64 u64 words/row)
#define NJC   8               // j-chunks for rank partials
#define MAXD 1000
#define IMGW 1280.0f
#define IMGH 1280.0f

// Fixed selection threshold: score >= 0.91 (= sigmoid(2.3136), f32 bits 0x3F68F5C3).
// desc key = 0x7FFFFFFF - float_bits(score), so pass <=> desc <= DSC_TH.
// Expected passers/image = 2382 +- 49; NMS examines ~1150 (25 sigma margin).
// Selection is prefix-closed for ANY threshold; sweep's Continuations A/B are exact
// fallbacks — correctness never depends on this constant, only speed.
#define DSC_TH 0x40970A3Cu

// ---- workspace layout (bytes) ----
#define BLKCNT_OFF 0                                   // u32 [BATCH*NBLK]
#define BLKVAL_OFF (BLKCNT_OFF + BATCH*NBLK*4)
#define BLKOFF_OFF (BLKVAL_OFF + BATCH*NBLK*4)
#define SELCNT_OFF (BLKOFF_OFF + BATCH*NBLK*4)         // u32 [BATCH]
#define TOTVAL_OFF (SELCNT_OFF + BATCH*4)
#define SCORE_OFF  65536                               // f32 [BATCH*NANCH]
#define DESC_OFF   (SCORE_OFF + BATCH*NANCH*4)         // u32 [BATCH*NANCH]
#define BOX_OFF    (DESC_OFF + BATCH*NANCH*4)          // float4 [BATCH*NANCH]
#define SELKEY_OFF (BOX_OFF + (size_t)BATCH*NANCH*16)  // u64 [BATCH*SELCAP]
#define SBOX_OFF   (SELKEY_OFF + (size_t)BATCH*SELCAP*8)
#define SSCORE_OFF (SBOX_OFF + (size_t)BATCH*SELCAP*16)
#define SAREA_OFF  (SSCORE_OFF + (size_t)BATCH*SELCAP*4)
#define PART_OFF   (SAREA_OFF + (size_t)BATCH*SELCAP*4)   // u32 [BATCH*SELCAP*NJC]
#define MASK_OFF   (PART_OFF + (size_t)BATCH*SELCAP*NJC*4) // u64 [BATCH*CPROC*64]

__device__ __forceinline__ u64 rdl64(u64 v, int l) {
    u32 lo = (u32)__builtin_amdgcn_readlane((int)(u32)(v & 0xFFFFFFFFull), l);
    u32 hi = (u32)__builtin_amdgcn_readlane((int)(u32)(v >> 32), l);
    return ((u64)hi << 32) | (u64)lo;
}

// Decode: sigmoid score, box decode+clip, validity, sortable key, per-block
// pass/valid counts via ballot (no atomics). All rounding-sensitive ops via
// __f*_rn to match numpy f32 op-by-op.
__global__ void decode_kernel(const float* __restrict__ obj,
                              const float4* __restrict__ deltas,
                              const float4* __restrict__ anchors,
                              float* __restrict__ score, u32* __restrict__ desc,
                              float4* __restrict__ boxes,
                              u32* __restrict__ blockcnt, u32* __restrict__ blockval) {
    int gid = blockIdx.x * blockDim.x + threadIdx.x;   // grid exact: 3600*256
    float4 a = anchors[gid];
    float4 d = deltas[gid];
    float o = obj[gid];
    float w = __fsub_rn(a.z, a.x), h = __fsub_rn(a.w, a.y);
    float cx = __fadd_rn(a.x, __fmul_rn(0.5f, w));
    float cy = __fadd_rn(a.y, __fmul_rn(0.5f, h));
    float px = __fadd_rn(__fmul_rn(d.x, w), cx);
    float py = __fadd_rn(__fmul_rn(d.y, h), cy);
    float pw = __fmul_rn(expf(fminf(d.z, 4.0f)), w);
    float ph = __fmul_rn(expf(fminf(d.w, 4.0f)), h);
    float x1 = __fsub_rn(px, __fmul_rn(0.5f, pw));
    float y1 = __fsub_rn(py, __fmul_rn(0.5f, ph));
    float x2 = __fadd_rn(px, __fmul_rn(0.5f, pw));
    float y2 = __fadd_rn(py, __fmul_rn(0.5f, ph));
    x1 = fminf(fmaxf(x1, 0.0f), IMGW); x2 = fminf(fmaxf(x2, 0.0f), IMGW);
    y1 = fminf(fmaxf(y1, 0.0f), IMGH); y2 = fminf(fmaxf(y2, 0.0f), IMGH);
    bool valid = (__fsub_rn(x2, x1) >= 1.0f) && (__fsub_rn(y2, y1) >= 1.0f);
    float s = __fdiv_rn(1.0f, __fadd_rn(1.0f, expf(-o)));  // matches np sigmoid branch
    boxes[gid] = make_float4(x1, y1, x2, y2);
    score[gid] = s;
    u32 dsc = valid ? (0x7FFFFFFFu - __float_as_uint(s)) : 0xFFFFFFFFu;
    desc[gid] = dsc;
    bool pass = dsc <= DSC_TH;
    u64 bp = __ballot(pass);
    u64 bv = __ballot(valid);
    __shared__ u32 wcnt[4], wval[4];
    int wid = threadIdx.x >> 6;
    if ((threadIdx.x & 63) == 0) { wcnt[wid] = (u32)__popcll(bp); wval[wid] = (u32)__popcll(bv); }
    __syncthreads();
    if (threadIdx.x == 0) {
        blockcnt[blockIdx.x] = wcnt[0] + wcnt[1] + wcnt[2] + wcnt[3];
        blockval[blockIdx.x] = wval[0] + wval[1] + wval[2] + wval[3];
    }
}

// Per-image exclusive prefix over the 900 block counts (one block per image).
__global__ void scan_kernel(const u32* __restrict__ blockcnt, const u32* __restrict__ blockval,
                            u32* __restrict__ blockoff, u32* __restrict__ selcnt,
                            u32* __restrict__ totval) {
    int img = blockIdx.x, t = threadIdx.x;   // 256 threads
    const u32* BC = blockcnt + img * NBLK;
    u32* BO = blockoff + img * NBLK;
    __shared__ u32 part[256], excl[256], tot;
    int i0 = t * 4;                           // 4*256 = 1024 >= 900
    u32 c[4], s = 0;
    for (int k = 0; k < 4; k++) { int i = i0 + k; c[k] = (i < NBLK) ? BC[i] : 0u; s += c[k]; }
    part[t] = s;
    __syncthreads();
    if (t == 0) {
        u32 run = 0;
        for (int k = 0; k < 256; k++) { excl[k] = run; run += part[k]; }
        tot = run;
    }
    __syncthreads();
    u32 run = excl[t];
    for (int k = 0; k < 4; k++) { int i = i0 + k; if (i < NBLK) BO[i] = run; run += c[k]; }
    if (t == 0) selcnt[img] = tot;
    __syncthreads();
    u32 v = 0;
    for (int k = 0; k < 4; k++) { int i = i0 + k; if (i < NBLK) v += blockval[img * NBLK + i]; }
    part[t] = v;
    __syncthreads();
    if (t == 0) {
        u32 r = 0;
        for (int k = 0; k < 256; k++) r += part[k];
        totval[img] = r;
    }
}

// Deterministic scatter: position = block offset + intra-block ballot prefix. No atomics.
__global__ void scatter_kernel(const u32* __restrict__ desc, const u32* __restrict__ blockoff,
                               u64* __restrict__ selkey) {
    int blk = blockIdx.x, tid = threadIdx.x;
    int gid = blk * 256 + tid;
    int img = blk / NBLK;
    u32 d = desc[gid];
    bool pass = d <= DSC_TH;
    u64 bal = __ballot(pass);
    int lane = tid & 63, wid = tid >> 6;
    __shared__ u32 woff[4];
    if (lane == 0) woff[wid] = (u32)__popcll(bal);
    __syncthreads();
    u32 wbase = 0;
    for (int w = 0; w < wid; w++) wbase += woff[w];
    if (pass) {
        u32 pos = blockoff[blk] + wbase + (u32)__popcll(bal & ((1ull << lane) - 1ull));
        if (pos < SELCAP)
            selkey[(size_t)img * SELCAP + pos] = ((u64)d << 32) | (u32)(gid - img * NANCH);
    }
}

// Rank pass 1: partial rank of item i against j-chunk jc, 8-wide unrolled LDS compares.
__global__ void rankpart_kernel(const u64* __restrict__ selkey, const u32* __restrict__ selcnt,
                                u32* __restrict__ partial) {
    int img = blockIdx.z;
    int C = min((int)selcnt[img], SELCAP);
    if ((int)(blockIdx.x * 256) >= C) return;
    int tid = threadIdx.x;
    int i = blockIdx.x * 256 + tid;
    int jc = blockIdx.y;
    int chunk = (C + NJC - 1) / NJC;
    int j0 = jc * chunk, j1 = min(j0 + chunk, C);
    const u64* K = selkey + (size_t)img * SELCAP;
    __shared__ u64 tile[1024];
    bool act = i < C;
    u64 my = act ? K[i] : ~0ull;
    u32 r = 0;
    for (int t0 = j0; t0 < j1; t0 += 1024) {
        int cnt = min(1024, j1 - t0);
        __syncthreads();
        for (int j = tid; j < cnt; j += 256) tile[j] = K[t0 + j];
        __syncthreads();
        int j = 0;
        for (; j + 8 <= cnt; j += 8) {
            u64 a0 = tile[j], a1 = tile[j+1], a2 = tile[j+2], a3 = tile[j+3];
            u64 a4 = tile[j+4], a5 = tile[j+5], a6 = tile[j+6], a7 = tile[j+7];
            r += (a0 < my) + (a1 < my) + (a2 < my) + (a3 < my)
               + (a4 < my) + (a5 < my) + (a6 < my) + (a7 < my);
        }
        for (; j < cnt; j++) r += (tile[j] < my) ? 1u : 0u;
    }
    if (act) partial[((size_t)img * SELCAP + i) * NJC + jc] = r;
}

// Rank pass 2: sum NJC partials -> final rank, gather box/score/area into sorted arrays.
__global__ void rankgather_kernel(const u64* __restrict__ selkey, const u32* __restrict__ selcnt,
                                  const u32* __restrict__ partial,
                                  const float4* __restrict__ boxes, const float* __restrict__ score,
                                  float4* __restrict__ sbox, float* __restrict__ sscore,
                                  float* __restrict__ sarea) {
    int img = blockIdx.y;
    int C = min((int)selcnt[img], SELCAP);
    if ((int)(blockIdx.x * 256) >= C) return;
    int i = blockIdx.x * 256 + threadIdx.x;
    if (i >= C) return;
    const u32* P = partial + ((size_t)img * SELCAP + i) * NJC;
    u32 rank = 0;
    #pragma unroll
    for (int k = 0; k < NJC; k++) rank += P[k];
    u64 my = selkey[(size_t)img * SELCAP + i];
    int ai = (int)(my & 0xFFFFFFFFu);
    int g = img * NANCH + ai;
    float4 bx = boxes[g];
    size_t o = (size_t)img * SELCAP + rank;
    sbox[o] = bx;
    sscore[o] = score[g];
    sarea[o] = __fmul_rn(fmaxf(__fsub_rn(bx.z, bx.x), 0.0f),
                         fmaxf(__fsub_rn(bx.w, bx.y), 0.0f));
}

// Pairwise IOU>0.5 bitmask over the first min(C,CPROC) sorted candidates.
// Rows are computed up to CeUp (= Ce rounded up to 64) so the sweep's unguarded
// 64-row loads never read poison: pad rows [Ce,CeUp) use a zero box -> all-zero bits.
__global__ void mask_kernel(const float4* __restrict__ sbox, const float* __restrict__ sarea,
                            const u32* __restrict__ selcnt, u64* __restrict__ mask) {
    int img = blockIdx.z;
    int C = min((int)selcnt[img], SELCAP);
    int Ce = min(C, CPROC);
    int CeUp = (Ce + 63) & ~63;
    if ((int)(blockIdx.x * 256) >= CeUp) return;
    int jtmax = (Ce + 63) >> 6;
    int jt0 = blockIdx.y * 8, jt1 = min(jt0 + 8, jtmax);
    if (jt0 >= jtmax) return;
    int i = blockIdx.x * 256 + threadIdx.x;
    const float4* SB = sbox + (size_t)img * SELCAP;
    const float* SA = sarea + (size_t)img * SELCAP;
    __shared__ float jx1[64], jy1[64], jx2[64], jy2[64], jar[64];
    bool act = i < CeUp;
    float4 bi = make_float4(0, 0, 0, 0);
    float ai_ = 0.0f;
    if (i < Ce) { bi = SB[i]; ai_ = SA[i]; }
    u64* Mrow = mask + ((size_t)img * CPROC + (size_t)i) * 64;
    for (int jt = jt0; jt < jt1; jt++) {
        int jbase = jt << 6;
        int jcnt = min(64, Ce - jbase);
        __syncthreads();
        if (threadIdx.x < 64) {
            int l = threadIdx.x;
            if (l < jcnt) {
                float4 b = SB[jbase + l];
                jx1[l] = b.x; jy1[l] = b.y; jx2[l] = b.z; jy2[l] = b.w;
                jar[l] = SA[jbase + l];
            } else {
                jx1[l] = 0; jy1[l] = 0; jx2[l] = 0; jy2[l] = 0; jar[l] = 0;
            }
        }
        __syncthreads();
        if (act) {
            u64 bits = 0;
            for (int jl = 0; jl < jcnt; jl++) {
                float ix1 = fmaxf(bi.x, jx1[jl]);
                float iy1 = fmaxf(bi.y, jy1[jl]);
                float ix2 = fminf(bi.z, jx2[jl]);
                float iy2 = fminf(bi.w, jy2[jl]);
                float inter = __fmul_rn(fmaxf(__fsub_rn(ix2, ix1), 0.0f),
                                        fmaxf(__fsub_rn(iy2, iy1), 0.0f));
                float den = __fadd_rn(__fsub_rn(__fadd_rn(ai_, jar[jl]), inter), 1e-9f);
                if (__fdiv_rn(inter, den) > 0.5f) bits |= (1ull << jl);
            }
            Mrow[jt] = bits;
        }
    }
}

__device__ __forceinline__ bool supp_by_acc(float4 bx, float ar, int acc, int lane,
                                            const float* ax1, const float* ay1,
                                            const float* ax2, const float* ay2,
                                            const float* aar) {
    bool hit = false;
    for (int k = lane; k < acc; k += 64) {
        float ix1 = fmaxf(bx.x, ax1[k]);
        float iy1 = fmaxf(bx.y, ay1[k]);
        float ix2 = fminf(bx.z, ax2[k]);
        float iy2 = fminf(bx.w, ay2[k]);
        float inter = __fmul_rn(fmaxf(__fsub_rn(ix2, ix1), 0.0f),
                                fmaxf(__fsub_rn(iy2, iy1), 0.0f));
        float den = __fadd_rn(__fsub_rn(__fadd_rn(aar[k], ar), inter), 1e-9f);
        if (__fdiv_rn(inter, den) > 0.5f) { hit = true; break; }
    }
    return __ballot(hit) != 0ull;
}

// Sweep v5: ONE wave per image, zero barriers.
// [R6 post-mortem: v4's u64 vals[64] (128 VGPR) was never materialized —
//  VGPR_Count=88 proves the compiler SANK each staging load into the readlane
//  chain, giving 64 serial ~120cy load-waits/iter ≈ 7.7k cy/iter = 104 us.
//  v5 decouples: (1) greedy resolve feeds on ONE diagonal gather load (tile),
//  scalar readlane chain ~500cy; (2) suppression ORs in 4 explicit batches of
//  16 named temps (<=32 VGPR live) combined branch-free via v & (0-bit) —
//  loads within a batch are forcibly grouped before use -> 4 latency windows.]
#define SWP_LD(k)  u64 v##k = Mrow0[(size_t)(k) * 64];
#define SWP_MS(k)  (v##k & (0ull - ((amg >> (k)) & 1ull)))
__global__ void __launch_bounds__(64, 1)
sweep_kernel(const float4* __restrict__ sbox, const float* __restrict__ sscore,
             const float* __restrict__ sarea, const u32* __restrict__ selcnt,
             const u32* __restrict__ totval, const u64* __restrict__ mask,
             const u64* __restrict__ selkey, const u32* __restrict__ descarr,
             const float4* __restrict__ boxes, const float* __restrict__ scorearr,
             float* __restrict__ out) {
    int img = blockIdx.x, lane = threadIdx.x;   // 64 threads = 1 wave
    int C = min((int)__builtin_amdgcn_readfirstlane((int)selcnt[img]), SELCAP);
    int Ce = min(C, CPROC);
    const float4* SB = sbox + (size_t)img * SELCAP;
    const float* SS = sscore + (size_t)img * SELCAP;
    const float* SA = sarea + (size_t)img * SELCAP;
    const u64* M = mask + (size_t)img * CPROC * 64;
    const u64* K = selkey + (size_t)img * SELCAP;
    __shared__ float ax1[MAXD], ay1[MAXD], ax2[MAXD], ay2[MAXD], aar[MAXD];
    float* ob = out + (size_t)img * MAXD * 4;
    float* os = out + (size_t)BATCH * MAXD * 4 + (size_t)img * MAXD;
    float* ov = out + (size_t)BATCH * MAXD * 5 + (size_t)img * MAXD;
    u64 sup = 0;                 // suppressed bitset: lane l holds word l
    int acc = 0;
    int nblk = (Ce + 63) >> 6;
    for (int ib = 0; ib < nblk && acc < MAXD; ib++) {
        int base = ib << 6;
        int bcount = min(64, Ce - base);
        const u64* Mb = M + (size_t)base * 64;
        // diagonal tile gather: lane b holds row (base+b)'s intra-block word
        u64 tile = Mb[(size_t)lane * 64 + ib];
        // exact greedy, branch-free scalar chain (uniform values in SGPRs)
        u64 cur = rdl64(sup, ib);
        u64 am = 0;
        int na = 0, keep = MAXD - acc;
        #pragma unroll
        for (int b = 0; b < 64; b++) {
            u64 row = rdl64(tile, b);
            u64 take = ((u64)(b < bcount) & (u64)(na < keep)) & (~(cur >> b) & 1ull);
            am |= take << b;
            na += (int)take;
            cur |= row & (0ull - take);
        }
        // suppression OR: 4 batches of 16 unconditional loads, mask-combined
        u64 orv = 0;
        #pragma unroll
        for (int g = 0; g < 4; g++) {
            const u64* Mrow0 = Mb + (size_t)(g << 4) * 64 + lane;
            u64 amg = am >> (g << 4);
            SWP_LD(0)  SWP_LD(1)  SWP_LD(2)  SWP_LD(3)
            SWP_LD(4)  SWP_LD(5)  SWP_LD(6)  SWP_LD(7)
            SWP_LD(8)  SWP_LD(9)  SWP_LD(10) SWP_LD(11)
            SWP_LD(12) SWP_LD(13) SWP_LD(14) SWP_LD(15)
            orv |= (SWP_MS(0)  | SWP_MS(1)  | SWP_MS(2)  | SWP_MS(3))
                 | (SWP_MS(4)  | SWP_MS(5)  | SWP_MS(6)  | SWP_MS(7))
                 | (SWP_MS(8)  | SWP_MS(9)  | SWP_MS(10) | SWP_MS(11))
                 | (SWP_MS(12) | SWP_MS(13) | SWP_MS(14) | SWP_MS(15));
        }
        sup |= orv;
        // lane-parallel outputs; no barrier -> latency drains in background
        if (lane < na) {
            u64 sel = am;
            for (int k = 0; k < lane; k++) sel &= sel - 1;
            int i = base + (int)__builtin_ctzll(sel);
            int o = acc + lane;
            float4 bx = SB[i];
            ((float4*)ob)[o] = bx;
            os[o] = SS[i]; ov[o] = 1.0f;
            ax1[o] = bx.x; ay1[o] = bx.y; ax2[o] = bx.z; ay2[o] = bx.w;
            aar[o] = SA[i];
        }
        acc += na;
    }
    // Continuation A (exact, ~never taken): selected candidates beyond the mask window.
    for (int i = Ce; i < C && acc < MAXD; i++) {
        float4 bx = SB[i];
        float ar = SA[i];
        if (!supp_by_acc(bx, ar, acc, lane, ax1, ay1, ax2, ay2, aar)) {
            if (lane == 0) {
                ob[acc * 4 + 0] = bx.x; ob[acc * 4 + 1] = bx.y;
                ob[acc * 4 + 2] = bx.z; ob[acc * 4 + 3] = bx.w;
                os[acc] = SS[i]; ov[acc] = 1.0f;
                ax1[acc] = bx.x; ay1[acc] = bx.y; ax2[acc] = bx.z; ay2[acc] = bx.w;
                aar[acc] = ar;
            }
            acc++;
        }
    }
    // Continuation B (exact deep fallback, ~never taken): valid candidates beyond selection.
    u32 tv = totval[img];
    if (acc < MAXD && (u32)C < tv && C < SELCAP) {
        u64 lk = 0;
        for (int j = lane; j < C; j += 64) lk = max(lk, K[j]);
        for (int off = 32; off; off >>= 1) { u64 o = __shfl_down(lk, off); lk = max(lk, o); }
        lk = __shfl(lk, 0);
        while (acc < MAXD) {
            u64 best = ~0ull;
            for (int j = lane; j < NANCH; j += 64) {
                u32 d = descarr[(size_t)img * NANCH + j];
                if (d != 0xFFFFFFFFu) {
                    u64 kk = ((u64)d << 32) | (u32)j;
                    if (kk > lk && kk < best) best = kk;
                }
            }
            for (int off = 32; off; off >>= 1) { u64 o = __shfl_down(best, off); best = min(best, o); }
            best = __shfl(best, 0);
            if (best == ~0ull) break;
            lk = best;
            int ai = (int)(best & 0xFFFFFFFFu);
            int g = img * NANCH + ai;
            float4 bx = boxes[g];
            float ar = __fmul_rn(fmaxf(__fsub_rn(bx.z, bx.x), 0.0f),
                                 fmaxf(__fsub_rn(bx.w, bx.y), 0.0f));
            if (!supp_by_acc(bx, ar, acc, lane, ax1, ay1, ax2, ay2, aar)) {
                if (lane == 0) {
                    ob[acc * 4 + 0] = bx.x; ob[acc * 4 + 1] = bx.y;
                    ob[acc * 4 + 2] = bx.z; ob[acc * 4 + 3] = bx.w;
                    os[acc] = scorearr[g]; ov[acc] = 1.0f;
                    ax1[acc] = bx.x; ay1[acc] = bx.y; ax2[acc] = bx.z; ay2[acc] = bx.w;
                    aar[acc] = ar;
                }
                acc++;
            }
        }
    }
}

extern "C" void kernel_launch(void* const* d_in, const int* in_sizes, int n_in,
                              void* d_out, int out_size, void* d_ws, size_t ws_size,
                              hipStream_t stream) {
    const float* obj = (const float*)d_in[0];
    const float4* deltas = (const float4*)d_in[1];
    const float4* anchors = (const float4*)d_in[2];
    char* ws = (char*)d_ws;
    u32* blockcnt = (u32*)(ws + BLKCNT_OFF);
    u32* blockval = (u32*)(ws + BLKVAL_OFF);
    u32* blockoff = (u32*)(ws + BLKOFF_OFF);
    u32* selcnt = (u32*)(ws + SELCNT_OFF);
    u32* totval = (u32*)(ws + TOTVAL_OFF);
    float* score = (float*)(ws + SCORE_OFF);
    u32* desc = (u32*)(ws + DESC_OFF);
    float4* boxes = (float4*)(ws + BOX_OFF);
    u64* selkey = (u64*)(ws + SELKEY_OFF);
    float4* sbox = (float4*)(ws + SBOX_OFF);
    float* sscore = (float*)(ws + SSCORE_OFF);
    float* sarea = (float*)(ws + SAREA_OFF);
    u32* partial = (u32*)(ws + PART_OFF);
    u64* mask = (u64*)(ws + MASK_OFF);
    float* out = (float*)d_out;

    hipMemsetAsync(d_out, 0, (size_t)out_size * sizeof(float), stream);    // zero-padded outputs

    decode_kernel<<<3600, 256, 0, stream>>>(obj, deltas, anchors, score, desc, boxes,
                                            blockcnt, blockval);
    scan_kernel<<<BATCH, 256, 0, stream>>>(blockcnt, blockval, blockoff, selcnt, totval);
    scatter_kernel<<<3600, 256, 0, stream>>>(desc, blockoff, selkey);
    rankpart_kernel<<<dim3(SELCAP / 256, NJC, BATCH), 256, 0, stream>>>(selkey, selcnt, partial);
    rankgather_kernel<<<dim3(SELCAP / 256, BATCH), 256, 0, stream>>>(selkey, selcnt, partial,
                                                                     boxes, score,
                                                                     sbox, sscore, sarea);
    mask_kernel<<<dim3(CPROC / 256, 8, BATCH), 256, 0, stream>>>(sbox, sarea, selcnt, mask);
    sweep_kernel<<<BATCH, 64, 0, stream>>>(sbox, sscore, sarea, selcnt, totval, mask,
                                           selkey, desc, boxes, score, out);
}

// Round 8
// 260.925 us; speedup vs baseline: 1.0482x; 1.0482x over previous
//
#include <hip/hip_runtime.h>
#include <stdint.h>

typedef unsigned long long u64;
typedef unsigned int u32;

#define BATCH 4
#define NANCH 230400          // 160*160*9
#define NBLK  900             // blocks of 256 per image (exact)
#define SELCAP 8192           // selection buffer cap per image
#define CPROC 2048            // candidates covered by pairwise bitmask
#define NW    32              // words per mask row = CPROC/64
#define NJC   8               // j-chunks for rank partials
#define MAXD 1000
#define IMGW 1280.0f
#define IMGH 1280.0f

// Fixed selection threshold: score >= 0.91 (= sigmoid(2.3136), f32 bits 0x3F68F5C3).
// desc key = 0x7FFFFFFF - float_bits(score); pass <=> desc <= DSC_TH.
// Expected passers/image = 2382 +- 49; NMS examines ~1150. Selection is
// prefix-closed for ANY threshold; Continuations A/B are exact fallbacks.
// CPROC=2048 covers the examined range (needing >2048 implies 51% suppression
// vs observed ~13%); Continuation A is the exact fallback if ever exceeded.
#define DSC_TH 0x40970A3Cu

// ---- workspace layout (bytes) ----
#define BLKCNT_OFF 0                                   // u32 [BATCH*NBLK]
#define BLKVAL_OFF (BLKCNT_OFF + BATCH*NBLK*4)
#define BLKOFF_OFF (BLKVAL_OFF + BATCH*NBLK*4)
#define SELCNT_OFF (BLKOFF_OFF + BATCH*NBLK*4)         // u32 [BATCH]
#define TOTVAL_OFF (SELCNT_OFF + BATCH*4)
#define SCORE_OFF  65536                               // f32 [BATCH*NANCH]
#define DESC_OFF   (SCORE_OFF + BATCH*NANCH*4)         // u32 [BATCH*NANCH]
#define BOX_OFF    (DESC_OFF + BATCH*NANCH*4)          // float4 [BATCH*NANCH]
#define SELKEY_OFF (BOX_OFF + (size_t)BATCH*NANCH*16)  // u64 [BATCH*SELCAP]
#define SBOX_OFF   (SELKEY_OFF + (size_t)BATCH*SELCAP*8)
#define SSCORE_OFF (SBOX_OFF + (size_t)BATCH*SELCAP*16)
#define SAREA_OFF  (SSCORE_OFF + (size_t)BATCH*SELCAP*4)
#define PART_OFF   (SAREA_OFF + (size_t)BATCH*SELCAP*4)   // u32 [BATCH*SELCAP*NJC]
#define MASK_OFF   (PART_OFF + (size_t)BATCH*SELCAP*NJC*4) // u64 [BATCH*CPROC*NW] = 2MB

__device__ __forceinline__ u64 rdl64(u64 v, int l) {
    u32 lo = (u32)__builtin_amdgcn_readlane((int)(u32)(v & 0xFFFFFFFFull), l);
    u32 hi = (u32)__builtin_amdgcn_readlane((int)(u32)(v >> 32), l);
    return ((u64)hi << 32) | (u64)lo;
}

// Decode: sigmoid score, box decode+clip, validity, sortable key, per-block
// pass/valid counts via ballot (no atomics). All rounding-sensitive ops via
// __f*_rn to match numpy f32 op-by-op.
__global__ void decode_kernel(const float* __restrict__ obj,
                              const float4* __restrict__ deltas,
                              const float4* __restrict__ anchors,
                              float* __restrict__ score, u32* __restrict__ desc,
                              float4* __restrict__ boxes,
                              u32* __restrict__ blockcnt, u32* __restrict__ blockval) {
    int gid = blockIdx.x * blockDim.x + threadIdx.x;   // grid exact: 3600*256
    float4 a = anchors[gid];
    float4 d = deltas[gid];
    float o = obj[gid];
    float w = __fsub_rn(a.z, a.x), h = __fsub_rn(a.w, a.y);
    float cx = __fadd_rn(a.x, __fmul_rn(0.5f, w));
    float cy = __fadd_rn(a.y, __fmul_rn(0.5f, h));
    float px = __fadd_rn(__fmul_rn(d.x, w), cx);
    float py = __fadd_rn(__fmul_rn(d.y, h), cy);
    float pw = __fmul_rn(expf(fminf(d.z, 4.0f)), w);
    float ph = __fmul_rn(expf(fminf(d.w, 4.0f)), h);
    float x1 = __fsub_rn(px, __fmul_rn(0.5f, pw));
    float y1 = __fsub_rn(py, __fmul_rn(0.5f, ph));
    float x2 = __fadd_rn(px, __fmul_rn(0.5f, pw));
    float y2 = __fadd_rn(py, __fmul_rn(0.5f, ph));
    x1 = fminf(fmaxf(x1, 0.0f), IMGW); x2 = fminf(fmaxf(x2, 0.0f), IMGW);
    y1 = fminf(fmaxf(y1, 0.0f), IMGH); y2 = fminf(fmaxf(y2, 0.0f), IMGH);
    bool valid = (__fsub_rn(x2, x1) >= 1.0f) && (__fsub_rn(y2, y1) >= 1.0f);
    float s = __fdiv_rn(1.0f, __fadd_rn(1.0f, expf(-o)));  // matches np sigmoid branch
    boxes[gid] = make_float4(x1, y1, x2, y2);
    score[gid] = s;
    u32 dsc = valid ? (0x7FFFFFFFu - __float_as_uint(s)) : 0xFFFFFFFFu;
    desc[gid] = dsc;
    bool pass = dsc <= DSC_TH;
    u64 bp = __ballot(pass);
    u64 bv = __ballot(valid);
    __shared__ u32 wcnt[4], wval[4];
    int wid = threadIdx.x >> 6;
    if ((threadIdx.x & 63) == 0) { wcnt[wid] = (u32)__popcll(bp); wval[wid] = (u32)__popcll(bv); }
    __syncthreads();
    if (threadIdx.x == 0) {
        blockcnt[blockIdx.x] = wcnt[0] + wcnt[1] + wcnt[2] + wcnt[3];
        blockval[blockIdx.x] = wval[0] + wval[1] + wval[2] + wval[3];
    }
}

// Per-image exclusive prefix over the 900 block counts (one block per image).
__global__ void scan_kernel(const u32* __restrict__ blockcnt, const u32* __restrict__ blockval,
                            u32* __restrict__ blockoff, u32* __restrict__ selcnt,
                            u32* __restrict__ totval) {
    int img = blockIdx.x, t = threadIdx.x;   // 256 threads
    const u32* BC = blockcnt + img * NBLK;
    u32* BO = blockoff + img * NBLK;
    __shared__ u32 part[256], excl[256], tot;
    int i0 = t * 4;                           // 4*256 = 1024 >= 900
    u32 c[4], s = 0;
    for (int k = 0; k < 4; k++) { int i = i0 + k; c[k] = (i < NBLK) ? BC[i] : 0u; s += c[k]; }
    part[t] = s;
    __syncthreads();
    if (t == 0) {
        u32 run = 0;
        for (int k = 0; k < 256; k++) { excl[k] = run; run += part[k]; }
        tot = run;
    }
    __syncthreads();
    u32 run = excl[t];
    for (int k = 0; k < 4; k++) { int i = i0 + k; if (i < NBLK) BO[i] = run; run += c[k]; }
    if (t == 0) selcnt[img] = tot;
    __syncthreads();
    u32 v = 0;
    for (int k = 0; k < 4; k++) { int i = i0 + k; if (i < NBLK) v += blockval[img * NBLK + i]; }
    part[t] = v;
    __syncthreads();
    if (t == 0) {
        u32 r = 0;
        for (int k = 0; k < 256; k++) r += part[k];
        totval[img] = r;
    }
}

// Deterministic scatter: position = block offset + intra-block ballot prefix. No atomics.
__global__ void scatter_kernel(const u32* __restrict__ desc, const u32* __restrict__ blockoff,
                               u64* __restrict__ selkey) {
    int blk = blockIdx.x, tid = threadIdx.x;
    int gid = blk * 256 + tid;
    int img = blk / NBLK;
    u32 d = desc[gid];
    bool pass = d <= DSC_TH;
    u64 bal = __ballot(pass);
    int lane = tid & 63, wid = tid >> 6;
    __shared__ u32 woff[4];
    if (lane == 0) woff[wid] = (u32)__popcll(bal);
    __syncthreads();
    u32 wbase = 0;
    for (int w = 0; w < wid; w++) wbase += woff[w];
    if (pass) {
        u32 pos = blockoff[blk] + wbase + (u32)__popcll(bal & ((1ull << lane) - 1ull));
        if (pos < SELCAP)
            selkey[(size_t)img * SELCAP + pos] = ((u64)d << 32) | (u32)(gid - img * NANCH);
    }
}

// Rank pass 1: partial rank of item i against j-chunk jc, 8-wide unrolled LDS compares.
__global__ void rankpart_kernel(const u64* __restrict__ selkey, const u32* __restrict__ selcnt,
                                u32* __restrict__ partial) {
    int img = blockIdx.z;
    int C = min((int)selcnt[img], SELCAP);
    if ((int)(blockIdx.x * 256) >= C) return;
    int tid = threadIdx.x;
    int i = blockIdx.x * 256 + tid;
    int jc = blockIdx.y;
    int chunk = (C + NJC - 1) / NJC;
    int j0 = jc * chunk, j1 = min(j0 + chunk, C);
    const u64* K = selkey + (size_t)img * SELCAP;
    __shared__ u64 tile[1024];
    bool act = i < C;
    u64 my = act ? K[i] : ~0ull;
    u32 r = 0;
    for (int t0 = j0; t0 < j1; t0 += 1024) {
        int cnt = min(1024, j1 - t0);
        __syncthreads();
        for (int j = tid; j < cnt; j += 256) tile[j] = K[t0 + j];
        __syncthreads();
        int j = 0;
        for (; j + 8 <= cnt; j += 8) {
            u64 a0 = tile[j], a1 = tile[j+1], a2 = tile[j+2], a3 = tile[j+3];
            u64 a4 = tile[j+4], a5 = tile[j+5], a6 = tile[j+6], a7 = tile[j+7];
            r += (a0 < my) + (a1 < my) + (a2 < my) + (a3 < my)
               + (a4 < my) + (a5 < my) + (a6 < my) + (a7 < my);
        }
        for (; j < cnt; j++) r += (tile[j] < my) ? 1u : 0u;
    }
    if (act) partial[((size_t)img * SELCAP + i) * NJC + jc] = r;
}

// Rank pass 2: sum NJC partials -> final rank, gather box/score/area into sorted arrays.
__global__ void rankgather_kernel(const u64* __restrict__ selkey, const u32* __restrict__ selcnt,
                                  const u32* __restrict__ partial,
                                  const float4* __restrict__ boxes, const float* __restrict__ score,
                                  float4* __restrict__ sbox, float* __restrict__ sscore,
                                  float* __restrict__ sarea) {
    int img = blockIdx.y;
    int C = min((int)selcnt[img], SELCAP);
    if ((int)(blockIdx.x * 256) >= C) return;
    int i = blockIdx.x * 256 + threadIdx.x;
    if (i >= C) return;
    const u32* P = partial + ((size_t)img * SELCAP + i) * NJC;
    u32 rank = 0;
    #pragma unroll
    for (int k = 0; k < NJC; k++) rank += P[k];
    u64 my = selkey[(size_t)img * SELCAP + i];
    int ai = (int)(my & 0xFFFFFFFFu);
    int g = img * NANCH + ai;
    float4 bx = boxes[g];
    size_t o = (size_t)img * SELCAP + rank;
    sbox[o] = bx;
    sscore[o] = score[g];
    sarea[o] = __fmul_rn(fmaxf(__fsub_rn(bx.z, bx.x), 0.0f),
                         fmaxf(__fsub_rn(bx.w, bx.y), 0.0f));
}

// Pairwise IOU>0.5 bitmask over the first min(C,CPROC) sorted candidates.
// NW=32 words/row (CPROC=2048). Rows computed to CeUp (64-aligned, zero-filled
// pads) so the sweep's unguarded row loads never read poison in words < jtmax.
__global__ void mask_kernel(const float4* __restrict__ sbox, const float* __restrict__ sarea,
                            const u32* __restrict__ selcnt, u64* __restrict__ mask) {
    int img = blockIdx.z;
    int C = min((int)selcnt[img], SELCAP);
    int Ce = min(C, CPROC);
    int CeUp = (Ce + 63) & ~63;
    if ((int)(blockIdx.x * 256) >= CeUp) return;
    int jtmax = (Ce + 63) >> 6;
    int jt0 = blockIdx.y * 8, jt1 = min(jt0 + 8, jtmax);
    if (jt0 >= jtmax) return;
    int i = blockIdx.x * 256 + threadIdx.x;
    const float4* SB = sbox + (size_t)img * SELCAP;
    const float* SA = sarea + (size_t)img * SELCAP;
    __shared__ float jx1[64], jy1[64], jx2[64], jy2[64], jar[64];
    bool act = i < CeUp;
    float4 bi = make_float4(0, 0, 0, 0);
    float ai_ = 0.0f;
    if (i < Ce) { bi = SB[i]; ai_ = SA[i]; }
    u64* Mrow = mask + ((size_t)img * CPROC + (size_t)i) * NW;
    for (int jt = jt0; jt < jt1; jt++) {
        int jbase = jt << 6;
        int jcnt = min(64, Ce - jbase);
        __syncthreads();
        if (threadIdx.x < 64) {
            int l = threadIdx.x;
            if (l < jcnt) {
                float4 b = SB[jbase + l];
                jx1[l] = b.x; jy1[l] = b.y; jx2[l] = b.z; jy2[l] = b.w;
                jar[l] = SA[jbase + l];
            } else {
                jx1[l] = 0; jy1[l] = 0; jx2[l] = 0; jy2[l] = 0; jar[l] = 0;
            }
        }
        __syncthreads();
        if (act) {
            u64 bits = 0;
            for (int jl = 0; jl < jcnt; jl++) {
                float ix1 = fmaxf(bi.x, jx1[jl]);
                float iy1 = fmaxf(bi.y, jy1[jl]);
                float ix2 = fminf(bi.z, jx2[jl]);
                float iy2 = fminf(bi.w, jy2[jl]);
                float inter = __fmul_rn(fmaxf(__fsub_rn(ix2, ix1), 0.0f),
                                        fmaxf(__fsub_rn(iy2, iy1), 0.0f));
                float den = __fadd_rn(__fsub_rn(__fadd_rn(ai_, jar[jl]), inter), 1e-9f);
                if (__fdiv_rn(inter, den) > 0.5f) bits |= (1ull << jl);
            }
            Mrow[jt] = bits;
        }
    }
}

// Sweep v6: 256 threads (4 waves), v3's proven load/barrier skeleton + v5's
// proven readlane-chain resolve + CPROC=2048 + deferred outputs.
// [R7 post-mortem: v4/v5 single-wave pipelining failed (compiler sinks load
//  batches; VGPR=88 both rounds). v3 (78us) already overlapped staging with
//  resolve — its cost was the ds-shfl fixpoint (~3-6k cy/iter). v6 keeps the
//  multi-wave skeleton (robust to sinking: waves 1-3's loads overlap wave 0's
//  resolve via wave-level parallelism) and swaps in the ~650cy scalar chain.
//  Outputs deferred to a post-loop bulk pass (removes SB gather from loop).]
__global__ void __launch_bounds__(256, 1)
sweep_kernel(const float4* __restrict__ sbox, const float* __restrict__ sscore,
             const float* __restrict__ sarea, const u32* __restrict__ selcnt,
             const u32* __restrict__ totval, const u64* __restrict__ mask,
             const u64* __restrict__ selkey, const u32* __restrict__ descarr,
             const float4* __restrict__ boxes, const float* __restrict__ scorearr,
             float* __restrict__ out) {
    int img = blockIdx.x;
    int tid = threadIdx.x, lane = tid & 63, wv = tid >> 6;   // 4 waves
    int C = min((int)selcnt[img], SELCAP);
    int Ce = min(C, CPROC);
    const float4* SB = sbox + (size_t)img * SELCAP;
    const float* SS = sscore + (size_t)img * SELCAP;
    const float* SA = sarea + (size_t)img * SELCAP;
    const u64* M = mask + (size_t)img * CPROC * NW;
    const u64* K = selkey + (size_t)img * SELCAP;
    __shared__ float ax1[MAXD], ay1[MAXD], ax2[MAXD], ay2[MAXD], aar[MAXD];
    __shared__ u64 sup4[4][NW];
    __shared__ u64 lds_am;
    __shared__ int lds_na;
    __shared__ int accidx[1024];
    __shared__ u64 red64[4];
    __shared__ int redi[4];
    float* ob = out + (size_t)img * MAXD * 4;
    float* os = out + (size_t)BATCH * MAXD * 4 + (size_t)img * MAXD;
    float* ov = out + (size_t)BATCH * MAXD * 5 + (size_t)img * MAXD;
    if (tid < 4 * NW) ((u64*)sup4)[tid] = 0;
    __syncthreads();
    u64 psup = 0;        // accumulated OR; word (tid&31), duplicated in both half-lanes
    int acc = 0;
    int nblk = (Ce + 63) >> 6;
    int row8 = tid >> 5;                 // base row-slot of this thread (0..7)
    u32 myw = (u32)(tid & 31);           // word owned by this thread
    for (int ib = 0; ib < nblk && acc < MAXD; ib++) {
        int base = ib << 6;
        int bcount = min(64, Ce - base);
        const u64* Mb = M + (size_t)base * NW;
        // unconditional staging: thread holds word myw of rows row8+8k, k=0..7
        // (element e = tid + 256k of the contiguous 16KB block tile)
        u64 s0 = Mb[tid];        u64 s1 = Mb[tid + 256];
        u64 s2 = Mb[tid + 512];  u64 s3 = Mb[tid + 768];
        u64 s4 = Mb[tid + 1024]; u64 s5 = Mb[tid + 1280];
        u64 s6 = Mb[tid + 1536]; u64 s7 = Mb[tid + 1792];
        if (wv == 0) {
            // diagonal gather (in flight alongside other waves' staging)
            u64 tile = Mb[(size_t)lane * NW + ib];
            u64 cur = sup4[0][ib] | sup4[1][ib] | sup4[2][ib] | sup4[3][ib];
            u64 am = 0;
            int na = 0, keep = MAXD - acc;
            #pragma unroll
            for (int b = 0; b < 64; b++) {
                u64 row = rdl64(tile, b);
                u64 take = ((u64)(b < bcount) & (u64)(na < keep)) & (~(cur >> b) & 1ull);
                am |= take << b;
                na += (int)take;
                cur |= row & (0ull - take);
            }
            if (lane == 0) { lds_am = am; lds_na = na; }
        }
        __syncthreads();
        u64 am = lds_am;
        int na = lds_na;
        // predicated OR of accepted rows (branch-free masks)
        psup |= s0 & (0ull - ((am >> (row8     )) & 1ull));
        psup |= s1 & (0ull - ((am >> (row8 +  8)) & 1ull));
        psup |= s2 & (0ull - ((am >> (row8 + 16)) & 1ull));
        psup |= s3 & (0ull - ((am >> (row8 + 24)) & 1ull));
        psup |= s4 & (0ull - ((am >> (row8 + 32)) & 1ull));
        psup |= s5 & (0ull - ((am >> (row8 + 40)) & 1ull));
        psup |= s6 & (0ull - ((am >> (row8 + 48)) & 1ull));
        psup |= s7 & (0ull - ((am >> (row8 + 56)) & 1ull));
        psup |= __shfl_xor(psup, 32);          // combine half-lanes (same word)
        if (lane < 32) sup4[wv][lane] = psup;
        // record accepted indices only; outputs deferred to post-loop bulk pass
        if (tid < na) {
            u64 sel = am;
            for (int k = 0; k < tid; k++) sel &= sel - 1;
            accidx[acc + tid] = base + (int)__builtin_ctzll(sel);
        }
        acc += na;
        __syncthreads();
    }
    // bulk output pass: 256-wide, fully pipelined
    for (int o = tid; o < acc; o += 256) {
        int i = accidx[o];
        float4 bx = SB[i];
        ((float4*)ob)[o] = bx;
        os[o] = SS[i]; ov[o] = 1.0f;
        ax1[o] = bx.x; ay1[o] = bx.y; ax2[o] = bx.z; ay2[o] = bx.w;
        aar[o] = SA[i];
    }
    __syncthreads();
    // Continuation A (exact, ~never taken): selected candidates beyond the mask window.
    for (int i = Ce; i < C && acc < MAXD; i++) {
        float4 bx = SB[i];
        float ar = SA[i];
        bool hit = false;
        for (int k = tid; k < acc; k += 256) {
            float ix1 = fmaxf(bx.x, ax1[k]);
            float iy1 = fmaxf(bx.y, ay1[k]);
            float ix2 = fminf(bx.z, ax2[k]);
            float iy2 = fminf(bx.w, ay2[k]);
            float inter = __fmul_rn(fmaxf(__fsub_rn(ix2, ix1), 0.0f),
                                    fmaxf(__fsub_rn(iy2, iy1), 0.0f));
            float den = __fadd_rn(__fsub_rn(__fadd_rn(aar[k], ar), inter), 1e-9f);
            if (__fdiv_rn(inter, den) > 0.5f) { hit = true; break; }
        }
        u64 bal = __ballot(hit);
        if (lane == 0) redi[wv] = (bal != 0ull) ? 1 : 0;
        __syncthreads();
        bool any = (redi[0] | redi[1] | redi[2] | redi[3]) != 0;
        __syncthreads();
        if (!any) {
            if (tid == 0) {
                ob[acc * 4 + 0] = bx.x; ob[acc * 4 + 1] = bx.y;
                ob[acc * 4 + 2] = bx.z; ob[acc * 4 + 3] = bx.w;
                os[acc] = SS[i]; ov[acc] = 1.0f;
                ax1[acc] = bx.x; ay1[acc] = bx.y; ax2[acc] = bx.z; ay2[acc] = bx.w;
                aar[acc] = ar;
            }
            __syncthreads();
            acc++;
        }
    }
    // Continuation B (exact deep fallback, ~never taken): valid candidates beyond selection.
    u32 tv = totval[img];
    if (acc < MAXD && (u32)C < tv && C < SELCAP) {
        u64 lk = 0;
        for (int j = tid; j < C; j += 256) lk = max(lk, K[j]);
        for (int off = 32; off; off >>= 1) { u64 o = __shfl_down(lk, off); lk = max(lk, o); }
        if (lane == 0) red64[wv] = lk;
        __syncthreads();
        lk = max(max(red64[0], red64[1]), max(red64[2], red64[3]));
        __syncthreads();
        while (acc < MAXD) {
            u64 best = ~0ull;
            for (int j = tid; j < NANCH; j += 256) {
                u32 d = descarr[(size_t)img * NANCH + j];
                if (d != 0xFFFFFFFFu) {
                    u64 kk = ((u64)d << 32) | (u32)j;
                    if (kk > lk && kk < best) best = kk;
                }
            }
            for (int off = 32; off; off >>= 1) { u64 o = __shfl_down(best, off); best = min(best, o); }
            if (lane == 0) red64[wv] = best;
            __syncthreads();
            best = min(min(red64[0], red64[1]), min(red64[2], red64[3]));
            __syncthreads();
            if (best == ~0ull) break;
            lk = best;
            int ai = (int)(best & 0xFFFFFFFFu);
            int g = img * NANCH + ai;
            float4 bx = boxes[g];
            float ar = __fmul_rn(fmaxf(__fsub_rn(bx.z, bx.x), 0.0f),
                                 fmaxf(__fsub_rn(bx.w, bx.y), 0.0f));
            bool hit = false;
            for (int k = tid; k < acc; k += 256) {
                float ix1 = fmaxf(bx.x, ax1[k]);
                float iy1 = fmaxf(bx.y, ay1[k]);
                float ix2 = fminf(bx.z, ax2[k]);
                float iy2 = fminf(bx.w, ay2[k]);
                float inter = __fmul_rn(fmaxf(__fsub_rn(ix2, ix1), 0.0f),
                                        fmaxf(__fsub_rn(iy2, iy1), 0.0f));
                float den = __fadd_rn(__fsub_rn(__fadd_rn(aar[k], ar), inter), 1e-9f);
                if (__fdiv_rn(inter, den) > 0.5f) { hit = true; break; }
            }
            u64 bal = __ballot(hit);
            if (lane == 0) redi[wv] = (bal != 0ull) ? 1 : 0;
            __syncthreads();
            bool any = (redi[0] | redi[1] | redi[2] | redi[3]) != 0;
            __syncthreads();
            if (!any) {
                if (tid == 0) {
                    ob[acc * 4 + 0] = bx.x; ob[acc * 4 + 1] = bx.y;
                    ob[acc * 4 + 2] = bx.z; ob[acc * 4 + 3] = bx.w;
                    os[acc] = scorearr[g]; ov[acc] = 1.0f;
                    ax1[acc] = bx.x; ay1[acc] = bx.y; ax2[acc] = bx.z; ay2[acc] = bx.w;
                    aar[acc] = ar;
                }
                __syncthreads();
                acc++;
            }
        }
    }
}

extern "C" void kernel_launch(void* const* d_in, const int* in_sizes, int n_in,
                              void* d_out, int out_size, void* d_ws, size_t ws_size,
                              hipStream_t stream) {
    const float* obj = (const float*)d_in[0];
    const float4* deltas = (const float4*)d_in[1];
    const float4* anchors = (const float4*)d_in[2];
    char* ws = (char*)d_ws;
    u32* blockcnt = (u32*)(ws + BLKCNT_OFF);
    u32* blockval = (u32*)(ws + BLKVAL_OFF);
    u32* blockoff = (u32*)(ws + BLKOFF_OFF);
    u32* selcnt = (u32*)(ws + SELCNT_OFF);
    u32* totval = (u32*)(ws + TOTVAL_OFF);
    float* score = (float*)(ws + SCORE_OFF);
    u32* desc = (u32*)(ws + DESC_OFF);
    float4* boxes = (float4*)(ws + BOX_OFF);
    u64* selkey = (u64*)(ws + SELKEY_OFF);
    float4* sbox = (float4*)(ws + SBOX_OFF);
    float* sscore = (float*)(ws + SSCORE_OFF);
    float* sarea = (float*)(ws + SAREA_OFF);
    u32* partial = (u32*)(ws + PART_OFF);
    u64* mask = (u64*)(ws + MASK_OFF);
    float* out = (float*)d_out;

    hipMemsetAsync(d_out, 0, (size_t)out_size * sizeof(float), stream);    // zero-padded outputs

    decode_kernel<<<3600, 256, 0, stream>>>(obj, deltas, anchors, score, desc, boxes,
                                            blockcnt, blockval);
    scan_kernel<<<BATCH, 256, 0, stream>>>(blockcnt, blockval, blockoff, selcnt, totval);
    scatter_kernel<<<3600, 256, 0, stream>>>(desc, blockoff, selkey);
    rankpart_kernel<<<dim3(SELCAP / 256, NJC, BATCH), 256, 0, stream>>>(selkey, selcnt, partial);
    rankgather_kernel<<<dim3(SELCAP / 256, BATCH), 256, 0, stream>>>(selkey, selcnt, partial,
                                                                     boxes, score,
                                                                     sbox, sscore, sarea);
    mask_kernel<<<dim3(CPROC / 256, 4, BATCH), 256, 0, stream>>>(sbox, sarea, selcnt, mask);
    sweep_kernel<<<BATCH, 256, 0, stream>>>(sbox, sscore, sarea, selcnt, totval, mask,
                                            selkey, desc, boxes, score, out);
}

// Round 9
// 254.992 us; speedup vs baseline: 1.0726x; 1.0233x over previous
//
#include <hip/hip_runtime.h>
#include <stdint.h>

typedef unsigned long long u64;
typedef unsigned int u32;

#define BATCH 4
#define NANCH 230400          // 160*160*9
#define NBLK  900             // blocks of 256 per image (exact)
#define SELCAP 8192           // selection buffer cap per image
#define CPROC 2048            // candidates covered by pairwise bitmask
#define NW    32              // words per mask row = CPROC/64
#define NJC   8               // j-chunks for rank partials
#define MAXD 1000
#define IMGW 1280.0f
#define IMGH 1280.0f

// Fixed selection threshold: score >= 0.91 (= sigmoid(2.3136), f32 bits 0x3F68F5C3).
// desc key = 0x7FFFFFFF - float_bits(score); pass <=> desc <= DSC_TH.
// Expected passers/image = 2382 +- 49; NMS examines ~1150. Selection is
// prefix-closed for ANY threshold; Continuations A/B are exact fallbacks.
#define DSC_TH 0x40970A3Cu

// ---- workspace layout (bytes) ----
#define BLKCNT_OFF 0                                   // u32 [BATCH*NBLK]
#define BLKVAL_OFF (BLKCNT_OFF + BATCH*NBLK*4)
#define BLKOFF_OFF (BLKVAL_OFF + BATCH*NBLK*4)
#define SELCNT_OFF (BLKOFF_OFF + BATCH*NBLK*4)         // u32 [BATCH]
#define TOTVAL_OFF (SELCNT_OFF + BATCH*4)
#define SCORE_OFF  65536                               // f32 [BATCH*NANCH]
#define DESC_OFF   (SCORE_OFF + BATCH*NANCH*4)         // u32 [BATCH*NANCH]
#define BOX_OFF    (DESC_OFF + BATCH*NANCH*4)          // float4 [BATCH*NANCH]
#define SELKEY_OFF (BOX_OFF + (size_t)BATCH*NANCH*16)  // u64 [BATCH*SELCAP]
#define SBOX_OFF   (SELKEY_OFF + (size_t)BATCH*SELCAP*8)
#define SSCORE_OFF (SBOX_OFF + (size_t)BATCH*SELCAP*16)
#define SAREA_OFF  (SSCORE_OFF + (size_t)BATCH*SELCAP*4)
#define PART_OFF   (SAREA_OFF + (size_t)BATCH*SELCAP*4)   // u32 [BATCH*SELCAP*NJC]
#define MASK_OFF   (PART_OFF + (size_t)BATCH*SELCAP*NJC*4) // u64 [BATCH*CPROC*NW] = 2MB

__device__ __forceinline__ u64 rdl64(u64 v, int l) {
    u32 lo = (u32)__builtin_amdgcn_readlane((int)(u32)(v & 0xFFFFFFFFull), l);
    u32 hi = (u32)__builtin_amdgcn_readlane((int)(u32)(v >> 32), l);
    return ((u64)hi << 32) | (u64)lo;
}

// Decode: sigmoid score, box decode+clip, validity, sortable key, per-block
// pass/valid counts via ballot (no atomics). All rounding-sensitive ops via
// __f*_rn to match numpy f32 op-by-op.
__global__ void decode_kernel(const float* __restrict__ obj,
                              const float4* __restrict__ deltas,
                              const float4* __restrict__ anchors,
                              float* __restrict__ score, u32* __restrict__ desc,
                              float4* __restrict__ boxes,
                              u32* __restrict__ blockcnt, u32* __restrict__ blockval) {
    int gid = blockIdx.x * blockDim.x + threadIdx.x;   // grid exact: 3600*256
    float4 a = anchors[gid];
    float4 d = deltas[gid];
    float o = obj[gid];
    float w = __fsub_rn(a.z, a.x), h = __fsub_rn(a.w, a.y);
    float cx = __fadd_rn(a.x, __fmul_rn(0.5f, w));
    float cy = __fadd_rn(a.y, __fmul_rn(0.5f, h));
    float px = __fadd_rn(__fmul_rn(d.x, w), cx);
    float py = __fadd_rn(__fmul_rn(d.y, h), cy);
    float pw = __fmul_rn(expf(fminf(d.z, 4.0f)), w);
    float ph = __fmul_rn(expf(fminf(d.w, 4.0f)), h);
    float x1 = __fsub_rn(px, __fmul_rn(0.5f, pw));
    float y1 = __fsub_rn(py, __fmul_rn(0.5f, ph));
    float x2 = __fadd_rn(px, __fmul_rn(0.5f, pw));
    float y2 = __fadd_rn(py, __fmul_rn(0.5f, ph));
    x1 = fminf(fmaxf(x1, 0.0f), IMGW); x2 = fminf(fmaxf(x2, 0.0f), IMGW);
    y1 = fminf(fmaxf(y1, 0.0f), IMGH); y2 = fminf(fmaxf(y2, 0.0f), IMGH);
    bool valid = (__fsub_rn(x2, x1) >= 1.0f) && (__fsub_rn(y2, y1) >= 1.0f);
    float s = __fdiv_rn(1.0f, __fadd_rn(1.0f, expf(-o)));  // matches np sigmoid branch
    boxes[gid] = make_float4(x1, y1, x2, y2);
    score[gid] = s;
    u32 dsc = valid ? (0x7FFFFFFFu - __float_as_uint(s)) : 0xFFFFFFFFu;
    desc[gid] = dsc;
    bool pass = dsc <= DSC_TH;
    u64 bp = __ballot(pass);
    u64 bv = __ballot(valid);
    __shared__ u32 wcnt[4], wval[4];
    int wid = threadIdx.x >> 6;
    if ((threadIdx.x & 63) == 0) { wcnt[wid] = (u32)__popcll(bp); wval[wid] = (u32)__popcll(bv); }
    __syncthreads();
    if (threadIdx.x == 0) {
        blockcnt[blockIdx.x] = wcnt[0] + wcnt[1] + wcnt[2] + wcnt[3];
        blockval[blockIdx.x] = wval[0] + wval[1] + wval[2] + wval[3];
    }
}

// Per-image exclusive prefix over the 900 block counts (one block per image).
__global__ void scan_kernel(const u32* __restrict__ blockcnt, const u32* __restrict__ blockval,
                            u32* __restrict__ blockoff, u32* __restrict__ selcnt,
                            u32* __restrict__ totval) {
    int img = blockIdx.x, t = threadIdx.x;   // 256 threads
    const u32* BC = blockcnt + img * NBLK;
    u32* BO = blockoff + img * NBLK;
    __shared__ u32 part[256], excl[256], tot;
    int i0 = t * 4;                           // 4*256 = 1024 >= 900
    u32 c[4], s = 0;
    for (int k = 0; k < 4; k++) { int i = i0 + k; c[k] = (i < NBLK) ? BC[i] : 0u; s += c[k]; }
    part[t] = s;
    __syncthreads();
    if (t == 0) {
        u32 run = 0;
        for (int k = 0; k < 256; k++) { excl[k] = run; run += part[k]; }
        tot = run;
    }
    __syncthreads();
    u32 run = excl[t];
    for (int k = 0; k < 4; k++) { int i = i0 + k; if (i < NBLK) BO[i] = run; run += c[k]; }
    if (t == 0) selcnt[img] = tot;
    __syncthreads();
    u32 v = 0;
    for (int k = 0; k < 4; k++) { int i = i0 + k; if (i < NBLK) v += blockval[img * NBLK + i]; }
    part[t] = v;
    __syncthreads();
    if (t == 0) {
        u32 r = 0;
        for (int k = 0; k < 256; k++) r += part[k];
        totval[img] = r;
    }
}

// Deterministic scatter: position = block offset + intra-block ballot prefix. No atomics.
__global__ void scatter_kernel(const u32* __restrict__ desc, const u32* __restrict__ blockoff,
                               u64* __restrict__ selkey) {
    int blk = blockIdx.x, tid = threadIdx.x;
    int gid = blk * 256 + tid;
    int img = blk / NBLK;
    u32 d = desc[gid];
    bool pass = d <= DSC_TH;
    u64 bal = __ballot(pass);
    int lane = tid & 63, wid = tid >> 6;
    __shared__ u32 woff[4];
    if (lane == 0) woff[wid] = (u32)__popcll(bal);
    __syncthreads();
    u32 wbase = 0;
    for (int w = 0; w < wid; w++) wbase += woff[w];
    if (pass) {
        u32 pos = blockoff[blk] + wbase + (u32)__popcll(bal & ((1ull << lane) - 1ull));
        if (pos < SELCAP)
            selkey[(size_t)img * SELCAP + pos] = ((u64)d << 32) | (u32)(gid - img * NANCH);
    }
}

// Rank pass 1: partial rank of item i against j-chunk jc, 8-wide unrolled LDS compares.
__global__ void rankpart_kernel(const u64* __restrict__ selkey, const u32* __restrict__ selcnt,
                                u32* __restrict__ partial) {
    int img = blockIdx.z;
    int C = min((int)selcnt[img], SELCAP);
    if ((int)(blockIdx.x * 256) >= C) return;
    int tid = threadIdx.x;
    int i = blockIdx.x * 256 + tid;
    int jc = blockIdx.y;
    int chunk = (C + NJC - 1) / NJC;
    int j0 = jc * chunk, j1 = min(j0 + chunk, C);
    const u64* K = selkey + (size_t)img * SELCAP;
    __shared__ u64 tile[1024];
    bool act = i < C;
    u64 my = act ? K[i] : ~0ull;
    u32 r = 0;
    for (int t0 = j0; t0 < j1; t0 += 1024) {
        int cnt = min(1024, j1 - t0);
        __syncthreads();
        for (int j = tid; j < cnt; j += 256) tile[j] = K[t0 + j];
        __syncthreads();
        int j = 0;
        for (; j + 8 <= cnt; j += 8) {
            u64 a0 = tile[j], a1 = tile[j+1], a2 = tile[j+2], a3 = tile[j+3];
            u64 a4 = tile[j+4], a5 = tile[j+5], a6 = tile[j+6], a7 = tile[j+7];
            r += (a0 < my) + (a1 < my) + (a2 < my) + (a3 < my)
               + (a4 < my) + (a5 < my) + (a6 < my) + (a7 < my);
        }
        for (; j < cnt; j++) r += (tile[j] < my) ? 1u : 0u;
    }
    if (act) partial[((size_t)img * SELCAP + i) * NJC + jc] = r;
}

// Rank pass 2: sum NJC partials -> final rank, gather box/score/area into sorted arrays.
__global__ void rankgather_kernel(const u64* __restrict__ selkey, const u32* __restrict__ selcnt,
                                  const u32* __restrict__ partial,
                                  const float4* __restrict__ boxes, const float* __restrict__ score,
                                  float4* __restrict__ sbox, float* __restrict__ sscore,
                                  float* __restrict__ sarea) {
    int img = blockIdx.y;
    int C = min((int)selcnt[img], SELCAP);
    if ((int)(blockIdx.x * 256) >= C) return;
    int i = blockIdx.x * 256 + threadIdx.x;
    if (i >= C) return;
    const u32* P = partial + ((size_t)img * SELCAP + i) * NJC;
    u32 rank = 0;
    #pragma unroll
    for (int k = 0; k < NJC; k++) rank += P[k];
    u64 my = selkey[(size_t)img * SELCAP + i];
    int ai = (int)(my & 0xFFFFFFFFu);
    int g = img * NANCH + ai;
    float4 bx = boxes[g];
    size_t o = (size_t)img * SELCAP + rank;
    sbox[o] = bx;
    sscore[o] = score[g];
    sarea[o] = __fmul_rn(fmaxf(__fsub_rn(bx.z, bx.x), 0.0f),
                         fmaxf(__fsub_rn(bx.w, bx.y), 0.0f));
}

// Pairwise IOU>0.5 bitmask over the first min(C,CPROC) sorted candidates.
// NW=32 words/row (CPROC=2048). Rows computed to CeUp (64-aligned, zero-filled
// pads) so the sweep's unguarded row loads never read poison in words < jtmax.
__global__ void mask_kernel(const float4* __restrict__ sbox, const float* __restrict__ sarea,
                            const u32* __restrict__ selcnt, u64* __restrict__ mask) {
    int img = blockIdx.z;
    int C = min((int)selcnt[img], SELCAP);
    int Ce = min(C, CPROC);
    int CeUp = (Ce + 63) & ~63;
    if ((int)(blockIdx.x * 256) >= CeUp) return;
    int jtmax = (Ce + 63) >> 6;
    int jt0 = blockIdx.y * 8, jt1 = min(jt0 + 8, jtmax);
    if (jt0 >= jtmax) return;
    int i = blockIdx.x * 256 + threadIdx.x;
    const float4* SB = sbox + (size_t)img * SELCAP;
    const float* SA = sarea + (size_t)img * SELCAP;
    __shared__ float jx1[64], jy1[64], jx2[64], jy2[64], jar[64];
    bool act = i < CeUp;
    float4 bi = make_float4(0, 0, 0, 0);
    float ai_ = 0.0f;
    if (i < Ce) { bi = SB[i]; ai_ = SA[i]; }
    u64* Mrow = mask + ((size_t)img * CPROC + (size_t)i) * NW;
    for (int jt = jt0; jt < jt1; jt++) {
        int jbase = jt << 6;
        int jcnt = min(64, Ce - jbase);
        __syncthreads();
        if (threadIdx.x < 64) {
            int l = threadIdx.x;
            if (l < jcnt) {
                float4 b = SB[jbase + l];
                jx1[l] = b.x; jy1[l] = b.y; jx2[l] = b.z; jy2[l] = b.w;
                jar[l] = SA[jbase + l];
            } else {
                jx1[l] = 0; jy1[l] = 0; jx2[l] = 0; jy2[l] = 0; jar[l] = 0;
            }
        }
        __syncthreads();
        if (act) {
            u64 bits = 0;
            for (int jl = 0; jl < jcnt; jl++) {
                float ix1 = fmaxf(bi.x, jx1[jl]);
                float iy1 = fmaxf(bi.y, jy1[jl]);
                float ix2 = fminf(bi.z, jx2[jl]);
                float iy2 = fminf(bi.w, jy2[jl]);
                float inter = __fmul_rn(fmaxf(__fsub_rn(ix2, ix1), 0.0f),
                                        fmaxf(__fsub_rn(iy2, iy1), 0.0f));
                float den = __fadd_rn(__fsub_rn(__fadd_rn(ai_, jar[jl]), inter), 1e-9f);
                if (__fdiv_rn(inter, den) > 0.5f) bits |= (1ull << jl);
            }
            Mrow[jt] = bits;
        }
    }
}

// Sweep v7 = v6 + EXPLICIT LOAD PINNING.
// [R8 post-mortem: v6 at 103us, VGPR=40 — the compiler sank the 8 staging
//  loads (legal: __restrict const memory, loads may move past __syncthreads)
//  to their uses in the OR phase -> 8 serial ~900cy L3-latency round-trips
//  per iter ≈ 13.7k cy/iter. Three rounds (v4/v5/v6) lost to this same
//  register-pressure heuristic. Fix: an empty `asm volatile` consuming all 9
//  loaded values ("+v") right after issue — forces all loads emitted before
//  that point with ONE s_waitcnt window, and pins values in VGPRs across the
//  barrier. Everything else byte-identical to the passing v6.]
__global__ void __launch_bounds__(256, 1)
sweep_kernel(const float4* __restrict__ sbox, const float* __restrict__ sscore,
             const float* __restrict__ sarea, const u32* __restrict__ selcnt,
             const u32* __restrict__ totval, const u64* __restrict__ mask,
             const u64* __restrict__ selkey, const u32* __restrict__ descarr,
             const float4* __restrict__ boxes, const float* __restrict__ scorearr,
             float* __restrict__ out) {
    int img = blockIdx.x;
    int tid = threadIdx.x, lane = tid & 63, wv = tid >> 6;   // 4 waves
    int C = min((int)selcnt[img], SELCAP);
    int Ce = min(C, CPROC);
    const float4* SB = sbox + (size_t)img * SELCAP;
    const float* SS = sscore + (size_t)img * SELCAP;
    const float* SA = sarea + (size_t)img * SELCAP;
    const u64* M = mask + (size_t)img * CPROC * NW;
    const u64* K = selkey + (size_t)img * SELCAP;
    __shared__ float ax1[MAXD], ay1[MAXD], ax2[MAXD], ay2[MAXD], aar[MAXD];
    __shared__ u64 sup4[4][NW];
    __shared__ u64 lds_am;
    __shared__ int lds_na;
    __shared__ int accidx[1024];
    __shared__ u64 red64[4];
    __shared__ int redi[4];
    float* ob = out + (size_t)img * MAXD * 4;
    float* os = out + (size_t)BATCH * MAXD * 4 + (size_t)img * MAXD;
    float* ov = out + (size_t)BATCH * MAXD * 5 + (size_t)img * MAXD;
    if (tid < 4 * NW) ((u64*)sup4)[tid] = 0;
    __syncthreads();
    u64 psup = 0;        // accumulated OR; word (tid&31), duplicated in both half-lanes
    int acc = 0;
    int nblk = (Ce + 63) >> 6;
    int row8 = tid >> 5;                 // base row-slot of this thread (0..7)
    for (int ib = 0; ib < nblk && acc < MAXD; ib++) {
        int base = ib << 6;
        int bcount = min(64, Ce - base);
        const u64* Mb = M + (size_t)base * NW;
        // issue diagonal gather (wave 0) + 8 staging loads back-to-back,
        // then PIN: one vmcnt window for all 9.
        u64 tile = 0;
        if (wv == 0) tile = Mb[(size_t)lane * NW + ib];
        u64 s0 = Mb[tid];        u64 s1 = Mb[tid + 256];
        u64 s2 = Mb[tid + 512];  u64 s3 = Mb[tid + 768];
        u64 s4 = Mb[tid + 1024]; u64 s5 = Mb[tid + 1280];
        u64 s6 = Mb[tid + 1536]; u64 s7 = Mb[tid + 1792];
        asm volatile("" : "+v"(s0), "+v"(s1), "+v"(s2), "+v"(s3),
                          "+v"(s4), "+v"(s5), "+v"(s6), "+v"(s7), "+v"(tile));
        if (wv == 0) {
            u64 cur = sup4[0][ib] | sup4[1][ib] | sup4[2][ib] | sup4[3][ib];
            u64 am = 0;
            int na = 0, keep = MAXD - acc;
            #pragma unroll
            for (int b = 0; b < 64; b++) {
                u64 row = rdl64(tile, b);
                u64 take = ((u64)(b < bcount) & (u64)(na < keep)) & (~(cur >> b) & 1ull);
                am |= take << b;
                na += (int)take;
                cur |= row & (0ull - take);
            }
            if (lane == 0) { lds_am = am; lds_na = na; }
        }
        __syncthreads();
        u64 am = lds_am;
        int na = lds_na;
        // predicated OR of accepted rows (branch-free masks)
        psup |= s0 & (0ull - ((am >> (row8     )) & 1ull));
        psup |= s1 & (0ull - ((am >> (row8 +  8)) & 1ull));
        psup |= s2 & (0ull - ((am >> (row8 + 16)) & 1ull));
        psup |= s3 & (0ull - ((am >> (row8 + 24)) & 1ull));
        psup |= s4 & (0ull - ((am >> (row8 + 32)) & 1ull));
        psup |= s5 & (0ull - ((am >> (row8 + 40)) & 1ull));
        psup |= s6 & (0ull - ((am >> (row8 + 48)) & 1ull));
        psup |= s7 & (0ull - ((am >> (row8 + 56)) & 1ull));
        psup |= __shfl_xor(psup, 32);          // combine half-lanes (same word)
        if (lane < 32) sup4[wv][lane] = psup;
        // record accepted indices only; outputs deferred to post-loop bulk pass
        if (tid < na) {
            u64 sel = am;
            for (int k = 0; k < tid; k++) sel &= sel - 1;
            accidx[acc + tid] = base + (int)__builtin_ctzll(sel);
        }
        acc += na;
        __syncthreads();
    }
    // bulk output pass: 256-wide, fully pipelined
    for (int o = tid; o < acc; o += 256) {
        int i = accidx[o];
        float4 bx = SB[i];
        ((float4*)ob)[o] = bx;
        os[o] = SS[i]; ov[o] = 1.0f;
        ax1[o] = bx.x; ay1[o] = bx.y; ax2[o] = bx.z; ay2[o] = bx.w;
        aar[o] = SA[i];
    }
    __syncthreads();
    // Continuation A (exact, ~never taken): selected candidates beyond the mask window.
    for (int i = Ce; i < C && acc < MAXD; i++) {
        float4 bx = SB[i];
        float ar = SA[i];
        bool hit = false;
        for (int k = tid; k < acc; k += 256) {
            float ix1 = fmaxf(bx.x, ax1[k]);
            float iy1 = fmaxf(bx.y, ay1[k]);
            float ix2 = fminf(bx.z, ax2[k]);
            float iy2 = fminf(bx.w, ay2[k]);
            float inter = __fmul_rn(fmaxf(__fsub_rn(ix2, ix1), 0.0f),
                                    fmaxf(__fsub_rn(iy2, iy1), 0.0f));
            float den = __fadd_rn(__fsub_rn(__fadd_rn(aar[k], ar), inter), 1e-9f);
            if (__fdiv_rn(inter, den) > 0.5f) { hit = true; break; }
        }
        u64 bal = __ballot(hit);
        if (lane == 0) redi[wv] = (bal != 0ull) ? 1 : 0;
        __syncthreads();
        bool any = (redi[0] | redi[1] | redi[2] | redi[3]) != 0;
        __syncthreads();
        if (!any) {
            if (tid == 0) {
                ob[acc * 4 + 0] = bx.x; ob[acc * 4 + 1] = bx.y;
                ob[acc * 4 + 2] = bx.z; ob[acc * 4 + 3] = bx.w;
                os[acc] = SS[i]; ov[acc] = 1.0f;
                ax1[acc] = bx.x; ay1[acc] = bx.y; ax2[acc] = bx.z; ay2[acc] = bx.w;
                aar[acc] = ar;
            }
            __syncthreads();
            acc++;
        }
    }
    // Continuation B (exact deep fallback, ~never taken): valid candidates beyond selection.
    u32 tv = totval[img];
    if (acc < MAXD && (u32)C < tv && C < SELCAP) {
        u64 lk = 0;
        for (int j = tid; j < C; j += 256) lk = max(lk, K[j]);
        for (int off = 32; off; off >>= 1) { u64 o = __shfl_down(lk, off); lk = max(lk, o); }
        if (lane == 0) red64[wv] = lk;
        __syncthreads();
        lk = max(max(red64[0], red64[1]), max(red64[2], red64[3]));
        __syncthreads();
        while (acc < MAXD) {
            u64 best = ~0ull;
            for (int j = tid; j < NANCH; j += 256) {
                u32 d = descarr[(size_t)img * NANCH + j];
                if (d != 0xFFFFFFFFu) {
                    u64 kk = ((u64)d << 32) | (u32)j;
                    if (kk > lk && kk < best) best = kk;
                }
            }
            for (int off = 32; off; off >>= 1) { u64 o = __shfl_down(best, off); best = min(best, o); }
            if (lane == 0) red64[wv] = best;
            __syncthreads();
            best = min(min(red64[0], red64[1]), min(red64[2], red64[3]));
            __syncthreads();
            if (best == ~0ull) break;
            lk = best;
            int ai = (int)(best & 0xFFFFFFFFu);
            int g = img * NANCH + ai;
            float4 bx = boxes[g];
            float ar = __fmul_rn(fmaxf(__fsub_rn(bx.z, bx.x), 0.0f),
                                 fmaxf(__fsub_rn(bx.w, bx.y), 0.0f));
            bool hit = false;
            for (int k = tid; k < acc; k += 256) {
                float ix1 = fmaxf(bx.x, ax1[k]);
                float iy1 = fmaxf(bx.y, ay1[k]);
                float ix2 = fminf(bx.z, ax2[k]);
                float iy2 = fminf(bx.w, ay2[k]);
                float inter = __fmul_rn(fmaxf(__fsub_rn(ix2, ix1), 0.0f),
                                        fmaxf(__fsub_rn(iy2, iy1), 0.0f));
                float den = __fadd_rn(__fsub_rn(__fadd_rn(aar[k], ar), inter), 1e-9f);
                if (__fdiv_rn(inter, den) > 0.5f) { hit = true; break; }
            }
            u64 bal = __ballot(hit);
            if (lane == 0) redi[wv] = (bal != 0ull) ? 1 : 0;
            __syncthreads();
            bool any = (redi[0] | redi[1] | redi[2] | redi[3]) != 0;
            __syncthreads();
            if (!any) {
                if (tid == 0) {
                    ob[acc * 4 + 0] = bx.x; ob[acc * 4 + 1] = bx.y;
                    ob[acc * 4 + 2] = bx.z; ob[acc * 4 + 3] = bx.w;
                    os[acc] = scorearr[g]; ov[acc] = 1.0f;
                    ax1[acc] = bx.x; ay1[acc] = bx.y; ax2[acc] = bx.z; ay2[acc] = bx.w;
                    aar[acc] = ar;
                }
                __syncthreads();
                acc++;
            }
        }
    }
}

extern "C" void kernel_launch(void* const* d_in, const int* in_sizes, int n_in,
                              void* d_out, int out_size, void* d_ws, size_t ws_size,
                              hipStream_t stream) {
    const float* obj = (const float*)d_in[0];
    const float4* deltas = (const float4*)d_in[1];
    const float4* anchors = (const float4*)d_in[2];
    char* ws = (char*)d_ws;
    u32* blockcnt = (u32*)(ws + BLKCNT_OFF);
    u32* blockval = (u32*)(ws + BLKVAL_OFF);
    u32* blockoff = (u32*)(ws + BLKOFF_OFF);
    u32* selcnt = (u32*)(ws + SELCNT_OFF);
    u32* totval = (u32*)(ws + TOTVAL_OFF);
    float* score = (float*)(ws + SCORE_OFF);
    u32* desc = (u32*)(ws + DESC_OFF);
    float4* boxes = (float4*)(ws + BOX_OFF);
    u64* selkey = (u64*)(ws + SELKEY_OFF);
    float4* sbox = (float4*)(ws + SBOX_OFF);
    float* sscore = (float*)(ws + SSCORE_OFF);
    float* sarea = (float*)(ws + SAREA_OFF);
    u32* partial = (u32*)(ws + PART_OFF);
    u64* mask = (u64*)(ws + MASK_OFF);
    float* out = (float*)d_out;

    hipMemsetAsync(d_out, 0, (size_t)out_size * sizeof(float), stream);    // zero-padded outputs

    decode_kernel<<<3600, 256, 0, stream>>>(obj, deltas, anchors, score, desc, boxes,
                                            blockcnt, blockval);
    scan_kernel<<<BATCH, 256, 0, stream>>>(blockcnt, blockval, blockoff, selcnt, totval);
    scatter_kernel<<<3600, 256, 0, stream>>>(desc, blockoff, selkey);
    rankpart_kernel<<<dim3(SELCAP / 256, NJC, BATCH), 256, 0, stream>>>(selkey, selcnt, partial);
    rankgather_kernel<<<dim3(SELCAP / 256, BATCH), 256, 0, stream>>>(selkey, selcnt, partial,
                                                                     boxes, score,
                                                                     sbox, sscore, sarea);
    mask_kernel<<<dim3(CPROC / 256, 4, BATCH), 256, 0, stream>>>(sbox, sarea, selcnt, mask);
    sweep_kernel<<<BATCH, 256, 0, stream>>>(sbox, sscore, sarea, selcnt, totval, mask,
                                            selkey, desc, boxes, score, out);
}

// Round 10
// 244.814 us; speedup vs baseline: 1.1172x; 1.0416x over previous
//
#include <hip/hip_runtime.h>
#include <stdint.h>

typedef unsigned long long u64;
typedef unsigned int u32;

#define BATCH 4
#define NANCH 230400          // 160*160*9
#define NBLK  900             // blocks of 256 per image (exact)
#define SELCAP 8192           // selection buffer cap per image
#define CPROC 2048            // candidates covered by pairwise bitmask
#define NW    32              // words per mask row = CPROC/64
#define NJC   8               // j-chunks for rank partials
#define MAXD 1000
#define IMGW 1280.0f
#define IMGH 1280.0f

// Fixed selection threshold: score >= 0.91 (= sigmoid(2.3136), f32 bits 0x3F68F5C3).
// desc key = 0x7FFFFFFF - float_bits(score); pass <=> desc <= DSC_TH.
// Expected passers/image = 2382 +- 49; NMS examines ~1150. Selection is
// prefix-closed for ANY threshold; Continuations A/B are exact fallbacks.
#define DSC_TH 0x40970A3Cu

// ---- workspace layout (bytes) ----
#define SELCNT_OFF 0                                   // u32 [BATCH] — memset 16B/launch
#define SCORE_OFF  256                                 // f32 [BATCH*NANCH]
#define DESC_OFF   (SCORE_OFF + BATCH*NANCH*4)         // u32 [BATCH*NANCH]
#define BOX_OFF    (DESC_OFF + BATCH*NANCH*4)          // float4 [BATCH*NANCH]
#define SELKEY_OFF (BOX_OFF + (size_t)BATCH*NANCH*16)  // u64 [BATCH*SELCAP]
#define SBOX_OFF   (SELKEY_OFF + (size_t)BATCH*SELCAP*8)
#define SSCORE_OFF (SBOX_OFF + (size_t)BATCH*SELCAP*16)
#define SAREA_OFF  (SSCORE_OFF + (size_t)BATCH*SELCAP*4)
#define PART_OFF   (SAREA_OFF + (size_t)BATCH*SELCAP*4)   // u32 [BATCH*SELCAP*NJC]
#define MASK_OFF   (PART_OFF + (size_t)BATCH*SELCAP*NJC*4) // u64 [BATCH*CPROC*NW]

// Decode FUSED with selection scatter [R9: scan+scatter nodes removed — graph
// node overhead ~13us each dominated the "rest"]. One atomicAdd per block
// (900/image over 4 independent words, ~35cy each, spread over decode's
// runtime). Storage order of selkey is arbitrary — ranksort orders by key
// VALUE, which is storage-order invariant. All rounding-sensitive ops via
// __f*_rn to match numpy f32 op-by-op.
__global__ void decode_kernel(const float* __restrict__ obj,
                              const float4* __restrict__ deltas,
                              const float4* __restrict__ anchors,
                              float* __restrict__ score, u32* __restrict__ desc,
                              float4* __restrict__ boxes,
                              u32* __restrict__ selcnt, u64* __restrict__ selkey) {
    int gid = blockIdx.x * blockDim.x + threadIdx.x;   // grid exact: 3600*256
    int img = gid / NANCH;                             // blocks don't straddle images
    float4 a = anchors[gid];
    float4 d = deltas[gid];
    float o = obj[gid];
    float w = __fsub_rn(a.z, a.x), h = __fsub_rn(a.w, a.y);
    float cx = __fadd_rn(a.x, __fmul_rn(0.5f, w));
    float cy = __fadd_rn(a.y, __fmul_rn(0.5f, h));
    float px = __fadd_rn(__fmul_rn(d.x, w), cx);
    float py = __fadd_rn(__fmul_rn(d.y, h), cy);
    float pw = __fmul_rn(expf(fminf(d.z, 4.0f)), w);
    float ph = __fmul_rn(expf(fminf(d.w, 4.0f)), h);
    float x1 = __fsub_rn(px, __fmul_rn(0.5f, pw));
    float y1 = __fsub_rn(py, __fmul_rn(0.5f, ph));
    float x2 = __fadd_rn(px, __fmul_rn(0.5f, pw));
    float y2 = __fadd_rn(py, __fmul_rn(0.5f, ph));
    x1 = fminf(fmaxf(x1, 0.0f), IMGW); x2 = fminf(fmaxf(x2, 0.0f), IMGW);
    y1 = fminf(fmaxf(y1, 0.0f), IMGH); y2 = fminf(fmaxf(y2, 0.0f), IMGH);
    bool valid = (__fsub_rn(x2, x1) >= 1.0f) && (__fsub_rn(y2, y1) >= 1.0f);
    float s = __fdiv_rn(1.0f, __fadd_rn(1.0f, expf(-o)));  // matches np sigmoid branch
    boxes[gid] = make_float4(x1, y1, x2, y2);
    score[gid] = s;
    u32 dsc = valid ? (0x7FFFFFFFu - __float_as_uint(s)) : 0xFFFFFFFFu;
    desc[gid] = dsc;
    bool pass = dsc <= DSC_TH;
    u64 bal = __ballot(pass);
    int lane = threadIdx.x & 63, wid = threadIdx.x >> 6;
    __shared__ u32 wcnt[4];
    __shared__ u32 sbase;
    if (lane == 0) wcnt[wid] = (u32)__popcll(bal);
    __syncthreads();
    if (threadIdx.x == 0) {
        u32 tot = wcnt[0] + wcnt[1] + wcnt[2] + wcnt[3];
        sbase = tot ? atomicAdd(&selcnt[img], tot) : 0u;
    }
    __syncthreads();
    if (pass) {
        u32 wbase = 0;
        for (int k = 0; k < wid; k++) wbase += wcnt[k];
        u32 pos = sbase + wbase + (u32)__popcll(bal & ((1ull << lane) - 1ull));
        if (pos < SELCAP)
            selkey[(size_t)img * SELCAP + pos] = ((u64)dsc << 32) | (u32)(gid - img * NANCH);
    }
}

// Rank pass 1: partial rank of item i against j-chunk jc, 8-wide unrolled LDS compares.
__global__ void rankpart_kernel(const u64* __restrict__ selkey, const u32* __restrict__ selcnt,
                                u32* __restrict__ partial) {
    int img = blockIdx.z;
    int C = min((int)selcnt[img], SELCAP);
    if ((int)(blockIdx.x * 256) >= C) return;
    int tid = threadIdx.x;
    int i = blockIdx.x * 256 + tid;
    int jc = blockIdx.y;
    int chunk = (C + NJC - 1) / NJC;
    int j0 = jc * chunk, j1 = min(j0 + chunk, C);
    const u64* K = selkey + (size_t)img * SELCAP;
    __shared__ u64 tile[1024];
    bool act = i < C;
    u64 my = act ? K[i] : ~0ull;
    u32 r = 0;
    for (int t0 = j0; t0 < j1; t0 += 1024) {
        int cnt = min(1024, j1 - t0);
        __syncthreads();
        for (int j = tid; j < cnt; j += 256) tile[j] = K[t0 + j];
        __syncthreads();
        int j = 0;
        for (; j + 8 <= cnt; j += 8) {
            u64 a0 = tile[j], a1 = tile[j+1], a2 = tile[j+2], a3 = tile[j+3];
            u64 a4 = tile[j+4], a5 = tile[j+5], a6 = tile[j+6], a7 = tile[j+7];
            r += (a0 < my) + (a1 < my) + (a2 < my) + (a3 < my)
               + (a4 < my) + (a5 < my) + (a6 < my) + (a7 < my);
        }
        for (; j < cnt; j++) r += (tile[j] < my) ? 1u : 0u;
    }
    if (act) partial[((size_t)img * SELCAP + i) * NJC + jc] = r;
}

// Rank pass 2: sum NJC partials -> final rank, gather box/score/area into sorted arrays.
__global__ void rankgather_kernel(const u64* __restrict__ selkey, const u32* __restrict__ selcnt,
                                  const u32* __restrict__ partial,
                                  const float4* __restrict__ boxes, const float* __restrict__ score,
                                  float4* __restrict__ sbox, float* __restrict__ sscore,
                                  float* __restrict__ sarea) {
    int img = blockIdx.y;
    int C = min((int)selcnt[img], SELCAP);
    if ((int)(blockIdx.x * 256) >= C) return;
    int i = blockIdx.x * 256 + threadIdx.x;
    if (i >= C) return;
    const u32* P = partial + ((size_t)img * SELCAP + i) * NJC;
    u32 rank = 0;
    #pragma unroll
    for (int k = 0; k < NJC; k++) rank += P[k];
    u64 my = selkey[(size_t)img * SELCAP + i];
    int ai = (int)(my & 0xFFFFFFFFu);
    int g = img * NANCH + ai;
    float4 bx = boxes[g];
    size_t o = (size_t)img * SELCAP + rank;
    sbox[o] = bx;
    sscore[o] = score[g];
    sarea[o] = __fmul_rn(fmaxf(__fsub_rn(bx.z, bx.x), 0.0f),
                         fmaxf(__fsub_rn(bx.w, bx.y), 0.0f));
}

// Pairwise IOU>0.5 bitmask over the first min(C,CPROC) sorted candidates.
// NW=32 words/row. Rows computed to CeUp (64-aligned, zero-filled pads).
__global__ void mask_kernel(const float4* __restrict__ sbox, const float* __restrict__ sarea,
                            const u32* __restrict__ selcnt, u64* __restrict__ mask) {
    int img = blockIdx.z;
    int C = min((int)selcnt[img], SELCAP);
    int Ce = min(C, CPROC);
    int CeUp = (Ce + 63) & ~63;
    if ((int)(blockIdx.x * 256) >= CeUp) return;
    int jtmax = (Ce + 63) >> 6;
    int jt0 = blockIdx.y * 8, jt1 = min(jt0 + 8, jtmax);
    if (jt0 >= jtmax) return;
    int i = blockIdx.x * 256 + threadIdx.x;
    const float4* SB = sbox + (size_t)img * SELCAP;
    const float* SA = sarea + (size_t)img * SELCAP;
    __shared__ float jx1[64], jy1[64], jx2[64], jy2[64], jar[64];
    bool act = i < CeUp;
    float4 bi = make_float4(0, 0, 0, 0);
    float ai_ = 0.0f;
    if (i < Ce) { bi = SB[i]; ai_ = SA[i]; }
    u64* Mrow = mask + ((size_t)img * CPROC + (size_t)i) * NW;
    for (int jt = jt0; jt < jt1; jt++) {
        int jbase = jt << 6;
        int jcnt = min(64, Ce - jbase);
        __syncthreads();
        if (threadIdx.x < 64) {
            int l = threadIdx.x;
            if (l < jcnt) {
                float4 b = SB[jbase + l];
                jx1[l] = b.x; jy1[l] = b.y; jx2[l] = b.z; jy2[l] = b.w;
                jar[l] = SA[jbase + l];
            } else {
                jx1[l] = 0; jy1[l] = 0; jx2[l] = 0; jy2[l] = 0; jar[l] = 0;
            }
        }
        __syncthreads();
        if (act) {
            u64 bits = 0;
            for (int jl = 0; jl < jcnt; jl++) {
                float ix1 = fmaxf(bi.x, jx1[jl]);
                float iy1 = fmaxf(bi.y, jy1[jl]);
                float ix2 = fminf(bi.z, jx2[jl]);
                float iy2 = fminf(bi.w, jy2[jl]);
                float inter = __fmul_rn(fmaxf(__fsub_rn(ix2, ix1), 0.0f),
                                        fmaxf(__fsub_rn(iy2, iy1), 0.0f));
                float den = __fadd_rn(__fsub_rn(__fadd_rn(ai_, jar[jl]), inter), 1e-9f);
                if (__fdiv_rn(inter, den) > 0.5f) bits |= (1ull << jl);
            }
            Mrow[jt] = bits;
        }
    }
}

// Sweep v8 = v7 skeleton + SPARSITY-DRIVEN RESOLVE.
// [R9 post-mortem: v7's 64-step readlane chain ≈ 800 dependent VALU/SALU instr
//  with readlane->SALU hazards ≈ 3-5k cy/iter run by one wave. Measured fact:
//  suppression ~13%, intra-block edges ~3% of that — per 64-block only ~8-12
//  bits have ANY incoming edge (ext | nonzero column). Column-empty bits are
//  PROVABLY accepted. New resolve: colOR = wave-OR-reduce of (tile & fut)
//  (6 shfl_xor), auto-accept ~(ext|colOR), then resolve only the flagged bits
//  ascending, each = one __ballot column extraction + AND test. Exact greedy.]
__global__ void __launch_bounds__(256, 1)
sweep_kernel(const float4* __restrict__ sbox, const float* __restrict__ sscore,
             const float* __restrict__ sarea, const u32* __restrict__ selcnt,
             const u64* __restrict__ mask, const u64* __restrict__ selkey,
             const u32* __restrict__ descarr, const float4* __restrict__ boxes,
             const float* __restrict__ scorearr, float* __restrict__ out) {
    int img = blockIdx.x;
    int tid = threadIdx.x, lane = tid & 63, wv = tid >> 6;   // 4 waves
    int C = min((int)selcnt[img], SELCAP);
    int Ce = min(C, CPROC);
    const float4* SB = sbox + (size_t)img * SELCAP;
    const float* SS = sscore + (size_t)img * SELCAP;
    const float* SA = sarea + (size_t)img * SELCAP;
    const u64* M = mask + (size_t)img * CPROC * NW;
    const u64* K = selkey + (size_t)img * SELCAP;
    __shared__ float ax1[MAXD], ay1[MAXD], ax2[MAXD], ay2[MAXD], aar[MAXD];
    __shared__ u64 sup4[4][NW];
    __shared__ u64 lds_am;
    __shared__ int lds_na;
    __shared__ int accidx[1024];
    __shared__ u64 red64[4];
    __shared__ int redi[4];
    float* ob = out + (size_t)img * MAXD * 4;
    float* os = out + (size_t)BATCH * MAXD * 4 + (size_t)img * MAXD;
    float* ov = out + (size_t)BATCH * MAXD * 5 + (size_t)img * MAXD;
    if (tid < 4 * NW) ((u64*)sup4)[tid] = 0;
    __syncthreads();
    u64 psup = 0;        // accumulated OR; word (tid&31), duplicated in both half-lanes
    int acc = 0;
    int nblk = (Ce + 63) >> 6;
    int row8 = tid >> 5;                 // base row-slot of this thread (0..7)
    for (int ib = 0; ib < nblk && acc < MAXD; ib++) {
        int base = ib << 6;
        int bcount = min(64, Ce - base);
        const u64* Mb = M + (size_t)base * NW;
        // issue diagonal gather (wave 0) + 8 staging loads back-to-back; pin.
        u64 tile = 0;
        if (wv == 0) tile = Mb[(size_t)lane * NW + ib];
        u64 s0 = Mb[tid];        u64 s1 = Mb[tid + 256];
        u64 s2 = Mb[tid + 512];  u64 s3 = Mb[tid + 768];
        u64 s4 = Mb[tid + 1024]; u64 s5 = Mb[tid + 1280];
        u64 s6 = Mb[tid + 1536]; u64 s7 = Mb[tid + 1792];
        asm volatile("" : "+v"(s0), "+v"(s1), "+v"(s2), "+v"(s3),
                          "+v"(s4), "+v"(s5), "+v"(s6), "+v"(s7), "+v"(tile));
        if (wv == 0) {
            u64 ext = sup4[0][ib] | sup4[1][ib] | sup4[2][ib] | sup4[3][ib];
            u64 range = (bcount == 64) ? ~0ull : ((1ull << bcount) - 1ull);
            // colOR: for each bit b, does ANY row l<b point at b?
            u64 fut = ~((2ull << lane) - 1ull);   // bits > lane (lane 63 -> 0)
            u64 t = tile & fut;
            #pragma unroll
            for (int off = 1; off < 64; off <<= 1) t |= __shfl_xor(t, off);
            u64 F = (ext | t) & range;            // bits with potential suppression
            u64 am = range & ~F;                  // column-empty & !ext => accepted
            u64 f = F;
            while (f) {                           // ~8-12 flagged bits typical
                int b = __builtin_ctzll(f); f &= f - 1;
                if ((ext >> b) & 1ull) continue;  // cross-block suppressed
                u64 colvec = __ballot((tile >> b) & 1ull);
                if ((colvec & am & ((1ull << b) - 1ull)) == 0ull) am |= 1ull << b;
            }
            int cnt = __popcll(am);
            int keep = MAXD - acc;
            while (cnt > keep) {                  // cap at 1000 (exact)
                am &= ~(1ull << (63 - __builtin_clzll(am)));
                cnt--;
            }
            if (lane == 0) { lds_am = am; lds_na = cnt; }
        }
        __syncthreads();
        u64 am = lds_am;
        int na = lds_na;
        // predicated OR of accepted rows (branch-free masks)
        psup |= s0 & (0ull - ((am >> (row8     )) & 1ull));
        psup |= s1 & (0ull - ((am >> (row8 +  8)) & 1ull));
        psup |= s2 & (0ull - ((am >> (row8 + 16)) & 1ull));
        psup |= s3 & (0ull - ((am >> (row8 + 24)) & 1ull));
        psup |= s4 & (0ull - ((am >> (row8 + 32)) & 1ull));
        psup |= s5 & (0ull - ((am >> (row8 + 40)) & 1ull));
        psup |= s6 & (0ull - ((am >> (row8 + 48)) & 1ull));
        psup |= s7 & (0ull - ((am >> (row8 + 56)) & 1ull));
        psup |= __shfl_xor(psup, 32);          // combine half-lanes (same word)
        if (lane < 32) sup4[wv][lane] = psup;
        // record accepted indices only; outputs deferred to post-loop bulk pass
        if (tid < na) {
            u64 sel = am;
            for (int k = 0; k < tid; k++) sel &= sel - 1;
            accidx[acc + tid] = base + (int)__builtin_ctzll(sel);
        }
        acc += na;
        __syncthreads();
    }
    // bulk output pass: 256-wide, fully pipelined
    for (int o = tid; o < acc; o += 256) {
        int i = accidx[o];
        float4 bx = SB[i];
        ((float4*)ob)[o] = bx;
        os[o] = SS[i]; ov[o] = 1.0f;
        ax1[o] = bx.x; ay1[o] = bx.y; ax2[o] = bx.z; ay2[o] = bx.w;
        aar[o] = SA[i];
    }
    __syncthreads();
    // Continuation A (exact, ~never taken): selected candidates beyond the mask window.
    for (int i = Ce; i < C && acc < MAXD; i++) {
        float4 bx = SB[i];
        float ar = SA[i];
        bool hit = false;
        for (int k = tid; k < acc; k += 256) {
            float ix1 = fmaxf(bx.x, ax1[k]);
            float iy1 = fmaxf(bx.y, ay1[k]);
            float ix2 = fminf(bx.z, ax2[k]);
            float iy2 = fminf(bx.w, ay2[k]);
            float inter = __fmul_rn(fmaxf(__fsub_rn(ix2, ix1), 0.0f),
                                    fmaxf(__fsub_rn(iy2, iy1), 0.0f));
            float den = __fadd_rn(__fsub_rn(__fadd_rn(aar[k], ar), inter), 1e-9f);
            if (__fdiv_rn(inter, den) > 0.5f) { hit = true; break; }
        }
        u64 bal = __ballot(hit);
        if (lane == 0) redi[wv] = (bal != 0ull) ? 1 : 0;
        __syncthreads();
        bool any = (redi[0] | redi[1] | redi[2] | redi[3]) != 0;
        __syncthreads();
        if (!any) {
            if (tid == 0) {
                ob[acc * 4 + 0] = bx.x; ob[acc * 4 + 1] = bx.y;
                ob[acc * 4 + 2] = bx.z; ob[acc * 4 + 3] = bx.w;
                os[acc] = SS[i]; ov[acc] = 1.0f;
                ax1[acc] = bx.x; ay1[acc] = bx.y; ax2[acc] = bx.z; ay2[acc] = bx.w;
                aar[acc] = ar;
            }
            __syncthreads();
            acc++;
        }
    }
    // Continuation B (exact deep fallback, ~never taken). Self-terminating: no totval.
    if (acc < MAXD) {
        u64 lk = 0;
        for (int j = tid; j < C; j += 256) lk = max(lk, K[j]);
        for (int off = 32; off; off >>= 1) { u64 o = __shfl_down(lk, off); lk = max(lk, o); }
        if (lane == 0) red64[wv] = lk;
        __syncthreads();
        lk = max(max(red64[0], red64[1]), max(red64[2], red64[3]));
        __syncthreads();
        while (acc < MAXD) {
            u64 best = ~0ull;
            for (int j = tid; j < NANCH; j += 256) {
                u32 d = descarr[(size_t)img * NANCH + j];
                if (d != 0xFFFFFFFFu) {
                    u64 kk = ((u64)d << 32) | (u32)j;
                    if (kk > lk && kk < best) best = kk;
                }
            }
            for (int off = 32; off; off >>= 1) { u64 o = __shfl_down(best, off); best = min(best, o); }
            if (lane == 0) red64[wv] = best;
            __syncthreads();
            best = min(min(red64[0], red64[1]), min(red64[2], red64[3]));
            __syncthreads();
            if (best == ~0ull) break;
            lk = best;
            int ai = (int)(best & 0xFFFFFFFFu);
            int g = img * NANCH + ai;
            float4 bx = boxes[g];
            float ar = __fmul_rn(fmaxf(__fsub_rn(bx.z, bx.x), 0.0f),
                                 fmaxf(__fsub_rn(bx.w, bx.y), 0.0f));
            bool hit = false;
            for (int k = tid; k < acc; k += 256) {
                float ix1 = fmaxf(bx.x, ax1[k]);
                float iy1 = fmaxf(bx.y, ay1[k]);
                float ix2 = fminf(bx.z, ax2[k]);
                float iy2 = fminf(bx.w, ay2[k]);
                float inter = __fmul_rn(fmaxf(__fsub_rn(ix2, ix1), 0.0f),
                                        fmaxf(__fsub_rn(iy2, iy1), 0.0f));
                float den = __fadd_rn(__fsub_rn(__fadd_rn(aar[k], ar), inter), 1e-9f);
                if (__fdiv_rn(inter, den) > 0.5f) { hit = true; break; }
            }
            u64 bal = __ballot(hit);
            if (lane == 0) redi[wv] = (bal != 0ull) ? 1 : 0;
            __syncthreads();
            bool any = (redi[0] | redi[1] | redi[2] | redi[3]) != 0;
            __syncthreads();
            if (!any) {
                if (tid == 0) {
                    ob[acc * 4 + 0] = bx.x; ob[acc * 4 + 1] = bx.y;
                    ob[acc * 4 + 2] = bx.z; ob[acc * 4 + 3] = bx.w;
                    os[acc] = scorearr[g]; ov[acc] = 1.0f;
                    ax1[acc] = bx.x; ay1[acc] = bx.y; ax2[acc] = bx.z; ay2[acc] = bx.w;
                    aar[acc] = ar;
                }
                __syncthreads();
                acc++;
            }
        }
    }
    // zero-fill tail slots [acc, MAXD) — replaces the d_out memset node.
    for (int o = acc + tid; o < MAXD; o += 256) {
        ((float4*)ob)[o] = make_float4(0, 0, 0, 0);
        os[o] = 0.0f; ov[o] = 0.0f;
    }
}

extern "C" void kernel_launch(void* const* d_in, const int* in_sizes, int n_in,
                              void* d_out, int out_size, void* d_ws, size_t ws_size,
                              hipStream_t stream) {
    const float* obj = (const float*)d_in[0];
    const float4* deltas = (const float4*)d_in[1];
    const float4* anchors = (const float4*)d_in[2];
    char* ws = (char*)d_ws;
    u32* selcnt = (u32*)(ws + SELCNT_OFF);
    float* score = (float*)(ws + SCORE_OFF);
    u32* desc = (u32*)(ws + DESC_OFF);
    float4* boxes = (float4*)(ws + BOX_OFF);
    u64* selkey = (u64*)(ws + SELKEY_OFF);
    float4* sbox = (float4*)(ws + SBOX_OFF);
    float* sscore = (float*)(ws + SSCORE_OFF);
    float* sarea = (float*)(ws + SAREA_OFF);
    u32* partial = (u32*)(ws + PART_OFF);
    u64* mask = (u64*)(ws + MASK_OFF);
    float* out = (float*)d_out;

    hipMemsetAsync(selcnt, 0, BATCH * sizeof(u32), stream);   // the only memset: 16 B

    decode_kernel<<<3600, 256, 0, stream>>>(obj, deltas, anchors, score, desc, boxes,
                                            selcnt, selkey);
    rankpart_kernel<<<dim3(SELCAP / 256, NJC, BATCH), 256, 0, stream>>>(selkey, selcnt, partial);
    rankgather_kernel<<<dim3(SELCAP / 256, BATCH), 256, 0, stream>>>(selkey, selcnt, partial,
                                                                     boxes, score,
                                                                     sbox, sscore, sarea);
    mask_kernel<<<dim3(CPROC / 256, 4, BATCH), 256, 0, stream>>>(sbox, sarea, selcnt, mask);
    sweep_kernel<<<BATCH, 256, 0, stream>>>(sbox, sscore, sarea, selcnt, mask,
                                            selkey, desc, boxes, score, out);
}